// Round 9
// baseline (933.196 us; speedup 1.0000x reference)
//
#include <hip/hip_runtime.h>

// ---------------- problem constants ----------------
#define NB      8
#define SEQ     4096
#define DM      512
#define DFF     2048
#define NE      8
#define NTOK    32768            // NB*SEQ
#define NPB     2097152          // SEQ*DM elems per batch
#define MAXROWS 66560            // 520 * 128 >= 65536 + 8*127
#define MAXTILES 520             // 128-row tiles

// output layout (fp32 elements)
#define OUT_LB   16777216
#define OUT_TOPK 16777217
#define OUT_TASK 16842753

// ws byte offsets
#define WS_BSTATS   0            // double[8][1024][2]
#define WS_DMEAN    131072
#define WS_DRSTD    131136
#define WS_DCOLSUM  131200
#define WS_DTASK    131264       // double[8][8]
#define WS_HIST     131776
#define WS_CURSOR   131808
#define WS_SEGOFF   131840
#define WS_HDR_END  131904
#define WS_ROUTE_E  131904       // int2[32768]
#define WS_ROUTE_P  394048       // float2[32768]
#define WS_ATOK     656192       // int[66560]
#define WS_APROB    922432       // float[66560]
#define WS_TOKPOS   1188672      // int[32768*2]
#define WS_W1T      1450816      // ushort[8*2048*512]
#define WS_W2T      18228032     // ushort[8*512*2048]
#define WS_XB       35005248     // ushort[32768*512]
#define WS_Y        68559680     // ushort[66560*512]
#define WS_H        136717120    // ushort[TPC*128*2048]

typedef __attribute__((ext_vector_type(4))) float  f32x4;
typedef __attribute__((ext_vector_type(8))) __bf16 bf16x8;
typedef __attribute__((ext_vector_type(8))) short  s16x8;

__device__ __forceinline__ unsigned short f2bf(float f) {
    unsigned int u = __builtin_bit_cast(unsigned int, f);
    u += 0x7FFFu + ((u >> 16) & 1u);
    return (unsigned short)(u >> 16);
}
__device__ __forceinline__ float bf2f(unsigned short b) {
    unsigned int u = ((unsigned int)b) << 16;
    return __builtin_bit_cast(float, u);
}
__device__ __forceinline__ unsigned int pkbf(float a, float b) {
    unsigned int r;
    asm("v_cvt_pk_bf16_f32 %0, %1, %2" : "=v"(r) : "v"(a), "v"(b));
    return r;
}

#define GLDS16(g, l)                                                              \
    __builtin_amdgcn_global_load_lds(                                             \
        (const __attribute__((address_space(1))) unsigned int*)(const void*)(g),  \
        (__attribute__((address_space(3))) unsigned int*)(void*)(l), 16, 0, 0)

// ---------------- weight transpose + bf16 convert ----------------
__global__ void k_transpose_bf16(const float* __restrict__ in,
                                 unsigned short* __restrict__ outT,
                                 int R, int C) {
    __shared__ float tile[32][33];
    int e = blockIdx.z;
    const float* src = in + (size_t)e * R * C;
    unsigned short* dst = outT + (size_t)e * R * C;
    int tx = threadIdx.x & 31, ty = threadIdx.x >> 5;
    int c0 = blockIdx.x * 32, r0 = blockIdx.y * 32;
#pragma unroll
    for (int i = 0; i < 4; i++) {
        int r = r0 + ty + i * 8;
        tile[ty + i * 8][tx] = src[(size_t)r * C + c0 + tx];
    }
    __syncthreads();
#pragma unroll
    for (int i = 0; i < 4; i++) {
        int rr = c0 + ty + i * 8;
        dst[(size_t)rr * R + r0 + tx] = f2bf(tile[tx][ty + i * 8]);
    }
}

// ---------------- fused: x -> bf16 copy + fp64 batch stats ----------------
__global__ void __launch_bounds__(256) k_xstats(const float* __restrict__ x,
                                                unsigned short* __restrict__ xb,
                                                double* __restrict__ bstats) {
    int b = blockIdx.y, cblk = blockIdx.x, t = threadIdx.x;
    size_t base = (size_t)b * NPB + (size_t)cblk * 2048 + (size_t)t * 8;
    float4 a = *(const float4*)(x + base);
    float4 v = *(const float4*)(x + base + 4);
    s16x8 o = {(short)f2bf(a.x), (short)f2bf(a.y), (short)f2bf(a.z), (short)f2bf(a.w),
               (short)f2bf(v.x), (short)f2bf(v.y), (short)f2bf(v.z), (short)f2bf(v.w)};
    *(s16x8*)(xb + base) = o;
    double s  = (double)a.x + (double)a.y + (double)a.z + (double)a.w
              + (double)v.x + (double)v.y + (double)v.z + (double)v.w;
    double ss = (double)a.x * a.x + (double)a.y * a.y + (double)a.z * a.z + (double)a.w * a.w
              + (double)v.x * v.x + (double)v.y * v.y + (double)v.z * v.z + (double)v.w * v.w;
    for (int o2 = 32; o2; o2 >>= 1) { s += __shfl_down(s, o2); ss += __shfl_down(ss, o2); }
    __shared__ double as_[4], ass_[4];
    int w = t >> 6;
    if ((t & 63) == 0) { as_[w] = s; ass_[w] = ss; }
    __syncthreads();
    if (t == 0) {
        s  = as_[0] + as_[1] + as_[2] + as_[3];
        ss = ass_[0] + ass_[1] + ass_[2] + ass_[3];
        bstats[(b * 1024 + cblk) * 2]     = s;
        bstats[(b * 1024 + cblk) * 2 + 1] = ss;
    }
}

// ---------------- finalize mean/rstd, gate colsum, task terms ----------------
__global__ void k_finalize(const double* __restrict__ bstats,
                           double* __restrict__ dmean, double* __restrict__ drstd,
                           double* __restrict__ dcolsum, double* __restrict__ dtask,
                           const float* __restrict__ gw, const float* __restrict__ gb,
                           const float* __restrict__ temb, const int* __restrict__ task_id,
                           float* __restrict__ out_task) {
    int t = threadIdx.x;
    int b = t >> 5, l = t & 31;
    double s = 0.0, ss = 0.0;
    for (int i = l; i < 1024; i += 32) {
        s  += bstats[(b * 1024 + i) * 2];
        ss += bstats[(b * 1024 + i) * 2 + 1];
    }
    for (int o = 16; o; o >>= 1) { s += __shfl_down(s, o, 32); ss += __shfl_down(ss, o, 32); }
    if (l == 0) {
        double N = (double)NPB;
        double m = s / N;
        double var = ss / N - m * m;
        dmean[b] = m;
        drstd[b] = 1.0 / sqrt(var + 1e-5);
    }
    __shared__ double colp[32][8];
    {
        int e = t & 7, g = t >> 3;
        double a = 0.0;
        for (int r = g * 16; r < g * 16 + 16; r++) a += (double)gw[r * 8 + e];
        colp[g][e] = a;
    }
    __syncthreads();
    if (t < 8) {
        double a = 0.0;
        for (int g = 0; g < 32; g++) a += colp[g][t];
        dcolsum[t] = a;
    }
    if (t < 64) {
        int b2 = t >> 3, e = t & 7;
        int tid = task_id[b2];
        double a = (double)gb[e];
        for (int d = 0; d < 64; d++)
            a += (double)temb[tid * 64 + d] * (double)gw[(512 + d) * 8 + e];
        dtask[t] = a;
    }
    if (t < 8) out_task[t] = (float)task_id[t];
}

// ---------------- gate: one THREAD per token (fp64, broadcast LDS reads) ----------------
__global__ void __launch_bounds__(256) k_gate(const float* __restrict__ x,
                                              const float* __restrict__ gw,
                                              const double* __restrict__ dmean,
                                              const double* __restrict__ drstd,
                                              const double* __restrict__ dcolsum,
                                              const double* __restrict__ dtask,
                                              int* __restrict__ hist,
                                              int2* __restrict__ route_e,
                                              float2* __restrict__ route_p,
                                              float* __restrict__ out_topk) {
    __shared__ float gws[DM * 8];
    __shared__ int lh[8];
    int t = threadIdx.x;
    if (t < 8) lh[t] = 0;
#pragma unroll
    for (int i = 0; i < 16; i++) gws[i * 256 + t] = gw[i * 256 + t];
    __syncthreads();

    int token = blockIdx.x * 256 + t;
    int b = token >> 12;
    const float4* xp = (const float4*)(x + (size_t)token * DM);

    double acc[8] = {0, 0, 0, 0, 0, 0, 0, 0};
#pragma unroll 2
    for (int i = 0; i < 128; i++) {
        float4 v = xp[i];
        double dx = v.x, dy = v.y, dz = v.z, dw = v.w;
        const float* g = &gws[i * 32];
#pragma unroll
        for (int e = 0; e < 8; e++)
            acc[e] += dx * (double)g[e] + dy * (double)g[8 + e]
                    + dz * (double)g[16 + e] + dw * (double)g[24 + e];
    }

    double m = dmean[b], rs = drstd[b];
    double lg[8];
#pragma unroll
    for (int e = 0; e < 8; e++) lg[e] = rs * (acc[e] - m * dcolsum[e]) + dtask[b * 8 + e];
    int i0 = 0;
#pragma unroll
    for (int e = 1; e < 8; e++) if (lg[e] > lg[i0]) i0 = e;
    int i1 = (i0 == 0) ? 1 : 0;
#pragma unroll
    for (int e = 0; e < 8; e++) if (e != i0 && lg[e] > lg[i1]) i1 = e;
    double d = exp(lg[i1] - lg[i0]);
    double p0 = 1.0 / (1.0 + d);
    double p1 = d / (1.0 + d);
    out_topk[token * 2]     = (float)i0;
    out_topk[token * 2 + 1] = (float)i1;
    atomicAdd(&lh[i0], 1);
    atomicAdd(&lh[i1], 1);
    route_e[token] = make_int2(i0, i1);
    route_p[token] = make_float2((float)p0, (float)p1);
    __syncthreads();
    if (t < 8) atomicAdd(&hist[t], lh[t]);
}

// ---------------- segment offsets (128-padded) + lb_loss ----------------
__global__ void k_offsets_lb(const int* __restrict__ hist, int* __restrict__ seg_off,
                             float* __restrict__ out_lb) {
    if (threadIdx.x == 0) {
        int off = 0;
        double ssd = 0.0;
        for (int e = 0; e < 8; e++) {
            seg_off[e] = off;
            off += (hist[e] + 127) & ~127;
            double d = (double)hist[e] - 8192.0;
            ssd += d * d;
        }
        seg_off[8] = off;
        double stdv = sqrt(ssd / 7.0);
        double m = 8192.0 + 1e-6;
        double r = stdv / m;
        *out_lb = (float)(r * r);
    }
}

// ---------------- scatter: LDS-aggregated two-level + inverse map ----------------
__global__ void __launch_bounds__(256) k_scatter(const int2* __restrict__ route_e,
                                                 const float2* __restrict__ route_p,
                                                 const int* __restrict__ seg_off,
                                                 int* __restrict__ cursor,
                                                 int* __restrict__ atok,
                                                 float* __restrict__ aprob,
                                                 int* __restrict__ tokpos) {
    __shared__ int lcount[8];
    __shared__ int lbase[8];
    int t = threadIdx.x;
    if (t < 8) lcount[t] = 0;
    __syncthreads();
    int tok = blockIdx.x * 256 + t;
    int2 e = route_e[tok];
    float2 p = route_p[tok];
    int p0 = atomicAdd(&lcount[e.x], 1);
    int p1 = atomicAdd(&lcount[e.y], 1);
    __syncthreads();
    if (t < 8) lbase[t] = atomicAdd(&cursor[t], lcount[t]);
    __syncthreads();
    int a0 = seg_off[e.x] + lbase[e.x] + p0;
    atok[a0] = tok; aprob[a0] = p.x;
    int a1 = seg_off[e.y] + lbase[e.y] + p1;
    atok[a1] = tok; aprob[a1] = p.y;
    tokpos[tok * 2]     = a0;
    tokpos[tok * 2 + 1] = a1;
}

// ============ Persistent 128x128 MFMA GEMMs, issue-early/wait-late, 1 barrier/K-tile ============
// LDS As/Bs[2][128][64] (64 KB -> 2 blocks/CU). XOR swizzle slot c holds chunk c^(row&7).
// Per K-tile kt: [issue stage kt+1 -> buf^1] [compute buf] [vmcnt(0)] [s_barrier].
// Last K-iter of a tile stages the NEXT tile's kt0 (fill paid once per block).
// mfma(bfv, af): lane's 4 acc elems = 4 consecutive OUTPUT COLUMNS.

#define STAGE8(UA, UB, KOF, LOF)                                    \
    _Pragma("unroll")                                               \
    for (int j_ = 0; j_ < 4; j_++) {                                \
        GLDS16(UA[j_] + (KOF), adst[j_] + (LOF));                   \
        GLDS16(UB[j_] + (KOF), bdst[j_] + (LOF));                   \
    }

#define COMPUTE_TILE(BUF)                                                          \
    {                                                                              \
        const unsigned short* Ab = &As[(BUF) * 8192];                              \
        const unsigned short* Bb = &Bs[(BUF) * 8192];                              \
        __builtin_amdgcn_s_setprio(1);                                             \
        _Pragma("unroll")                                                          \
        for (int h = 0; h < 2; h++) {                                              \
            bf16x8 af[4], bfv[4];                                                  \
            _Pragma("unroll")                                                      \
            for (int m = 0; m < 4; m++) {                                          \
                int R = wr * 64 + m * 16 + lr;                                     \
                af[m] = *(const bf16x8*)&Ab[R * 64 + (((h << 2) + q) ^ (R & 7)) * 8]; \
            }                                                                      \
            _Pragma("unroll")                                                      \
            for (int n = 0; n < 4; n++) {                                          \
                int R = wc * 64 + n * 16 + lr;                                     \
                bfv[n] = *(const bf16x8*)&Bb[R * 64 + (((h << 2) + q) ^ (R & 7)) * 8]; \
            }                                                                      \
            _Pragma("unroll")                                                      \
            for (int m = 0; m < 4; m++)                                            \
                _Pragma("unroll")                                                  \
                for (int n = 0; n < 4; n++)                                        \
                    acc[m][n] = __builtin_amdgcn_mfma_f32_16x16x32_bf16(bfv[n], af[m], acc[m][n], 0, 0, 0); \
        }                                                                          \
        __builtin_amdgcn_s_setprio(0);                                             \
    }

// ---------------- GEMM1: H[chunk] = silu(X_gather @ w1[e] + b1[e]) ----------------
__global__ void __launch_bounds__(256) k_gemm1(const unsigned short* __restrict__ xb,
                                               const unsigned short* __restrict__ w1t,
                                               const float* __restrict__ b1,
                                               const int* __restrict__ atok,
                                               const int* __restrict__ seg_off,
                                               unsigned short* __restrict__ H,
                                               int t0, int tpc, int maxt) {
    int rows_end = seg_off[8];
    int tpc_eff = maxt - t0; if (tpc_eff > tpc) tpc_eff = tpc;
    int xtv = rows_end / 128 - t0;
    if (xtv > tpc_eff) xtv = tpc_eff;
    if (xtv <= 0) return;
    int nt = xtv * 16;
    int G = (int)gridDim.x;
    int T = (nt + G - 1) / G;
    int wg0 = (int)blockIdx.x * T;
    int wg1 = wg0 + T; if (wg1 > nt) wg1 = nt;
    if (wg0 >= wg1) return;

    int tid = threadIdx.x;
    int w = tid >> 6, l = tid & 63;
    int c = l & 7;
    int wr = w >> 1, wc = w & 1, lr = l & 15, q = l >> 4;

    __shared__ __align__(16) unsigned short As[2 * 128 * 64];
    __shared__ __align__(16) unsigned short Bs[2 * 128 * 64];
    unsigned short* adst[4];
    unsigned short* bdst[4];
#pragma unroll
    for (int j = 0; j < 4; j++) {
        adst[j] = &As[(w * 32 + j * 8) * 64];
        bdst[j] = &Bs[(w * 32 + j * 8) * 64];
    }

    const unsigned short* cura[4];
    const unsigned short* curb[4];
    const unsigned short* nxta[4];
    const unsigned short* nxtb[4];

    // address calc for tile wg
    auto calc = [&](int wg, const unsigned short* (&ua)[4], const unsigned short* (&ub)[4]) {
        int xt = wg >> 4, y = wg & 15;
        int r0 = (t0 + xt) * 128;
        int e = 0;
        while (seg_off[e + 1] <= r0) e++;
        int f0 = y * 128;
#pragma unroll
        for (int j = 0; j < 4; j++) {
            int row = w * 32 + j * 8 + (l >> 3);
            int cs = c ^ (row & 7);
            int tok = atok[r0 + row]; if (tok < 0) tok = 0;
            ua[j] = xb + (size_t)tok * DM + cs * 8;
            ub[j] = w1t + ((size_t)e * DFF + f0 + row) * DM + cs * 8;
        }
    };

    calc(wg0, cura, curb);
    STAGE8(cura, curb, 0, 0);
    asm volatile("s_waitcnt vmcnt(0)" ::: "memory");
    __builtin_amdgcn_s_barrier();
    __builtin_amdgcn_sched_barrier(0);

    for (int t = wg0; t < wg1; ++t) {
        int more = (t + 1 < wg1);
        if (more) calc(t + 1, nxta, nxtb);

        f32x4 acc[4][4] = {};
#pragma unroll
        for (int kt = 0; kt < 8; ++kt) {
            if (kt < 7) {
                STAGE8(cura, curb, (kt + 1) * 64, ((kt + 1) & 1) * 8192);
            } else if (more) {
                STAGE8(nxta, nxtb, 0, 0);
            }
            __builtin_amdgcn_sched_barrier(0);
            COMPUTE_TILE(kt & 1);
            __builtin_amdgcn_sched_barrier(0);
            asm volatile("s_waitcnt vmcnt(0)" ::: "memory");
            __builtin_amdgcn_s_barrier();
            __builtin_amdgcn_sched_barrier(0);
        }

        // epilogue: acc[m][n][j] -> H row (wr*64+m*16+lr), col f0 + wc*64+n*16+q*4+j
        {
            int xt = t >> 4, y = t & 15;
            int r0 = (t0 + xt) * 128;
            int e = 0;
            while (seg_off[e + 1] <= r0) e++;
            int f0 = y * 128;
            const float* b1e = b1 + e * DFF + f0;
#pragma unroll
            for (int m = 0; m < 4; m++) {
                int r = wr * 64 + m * 16 + lr;
                unsigned short* hrow = H + ((size_t)xt * 128 + r) * DFF + f0;
#pragma unroll
                for (int n = 0; n < 4; n++) {
                    int fc = wc * 64 + n * 16 + q * 4;
                    float4 bias = *(const float4*)(b1e + fc);
                    float v0 = acc[m][n][0] + bias.x; v0 = v0 / (1.0f + __expf(-v0));
                    float v1 = acc[m][n][1] + bias.y; v1 = v1 / (1.0f + __expf(-v1));
                    float v2 = acc[m][n][2] + bias.z; v2 = v2 / (1.0f + __expf(-v2));
                    float v3 = acc[m][n][3] + bias.w; v3 = v3 / (1.0f + __expf(-v3));
                    *(uint2*)(hrow + fc) = make_uint2(pkbf(v0, v1), pkbf(v2, v3));
                }
            }
        }
        if (more) {
#pragma unroll
            for (int j = 0; j < 4; j++) { cura[j] = nxta[j]; curb[j] = nxtb[j]; }
        }
    }
}

// ---------------- GEMM2: Y[aidx] = H[chunk] @ w2[e]  (K=2048) ----------------
__global__ void __launch_bounds__(256) k_gemm2(const unsigned short* __restrict__ H,
                                               const unsigned short* __restrict__ w2t,
                                               const int* __restrict__ seg_off,
                                               unsigned short* __restrict__ Y,
                                               int t0, int tpc, int maxt) {
    int rows_end = seg_off[8];
    int tpc_eff = maxt - t0; if (tpc_eff > tpc) tpc_eff = tpc;
    int xtv = rows_end / 128 - t0;
    if (xtv > tpc_eff) xtv = tpc_eff;
    if (xtv <= 0) return;
    int nt = xtv * 4;
    int G = (int)gridDim.x;
    int T = (nt + G - 1) / G;
    int wg0 = (int)blockIdx.x * T;
    int wg1 = wg0 + T; if (wg1 > nt) wg1 = nt;
    if (wg0 >= wg1) return;

    int tid = threadIdx.x;
    int w = tid >> 6, l = tid & 63;
    int c = l & 7;
    int wr = w >> 1, wc = w & 1, lr = l & 15, q = l >> 4;

    __shared__ __align__(16) unsigned short As[2 * 128 * 64];
    __shared__ __align__(16) unsigned short Bs[2 * 128 * 64];
    unsigned short* adst[4];
    unsigned short* bdst[4];
#pragma unroll
    for (int j = 0; j < 4; j++) {
        adst[j] = &As[(w * 32 + j * 8) * 64];
        bdst[j] = &Bs[(w * 32 + j * 8) * 64];
    }

    const unsigned short* cura[4];
    const unsigned short* curb[4];
    const unsigned short* nxta[4];
    const unsigned short* nxtb[4];

    auto calc = [&](int wg, const unsigned short* (&ua)[4], const unsigned short* (&ub)[4]) {
        int xt = wg >> 2, y = wg & 3;
        int r0 = (t0 + xt) * 128;
        int e = 0;
        while (seg_off[e + 1] <= r0) e++;
        int d0 = y * 128;
#pragma unroll
        for (int j = 0; j < 4; j++) {
            int row = w * 32 + j * 8 + (l >> 3);
            int cs = c ^ (row & 7);
            ua[j] = H + ((size_t)xt * 128 + row) * DFF + cs * 8;
            ub[j] = w2t + ((size_t)e * DM + d0 + row) * DFF + cs * 8;
        }
    };

    calc(wg0, cura, curb);
    STAGE8(cura, curb, 0, 0);
    asm volatile("s_waitcnt vmcnt(0)" ::: "memory");
    __builtin_amdgcn_s_barrier();
    __builtin_amdgcn_sched_barrier(0);

    for (int t = wg0; t < wg1; ++t) {
        int more = (t + 1 < wg1);
        if (more) calc(t + 1, nxta, nxtb);

        f32x4 acc[4][4] = {};
        for (int kt = 0; kt < 32; ++kt) {           // K = 2048
            if (kt < 31) {
                STAGE8(cura, curb, (kt + 1) * 64, ((kt + 1) & 1) * 8192);
            } else if (more) {
                STAGE8(nxta, nxtb, 0, 0);
            }
            __builtin_amdgcn_sched_barrier(0);
            COMPUTE_TILE(kt & 1);
            __builtin_amdgcn_sched_barrier(0);
            asm volatile("s_waitcnt vmcnt(0)" ::: "memory");
            __builtin_amdgcn_s_barrier();
            __builtin_amdgcn_sched_barrier(0);
        }

        // epilogue: acc[m][n][j] -> Y row (wr*64+m*16+lr), col d0 + wc*64+n*16+q*4+j
        {
            int xt = t >> 2, y = t & 3;
            int r0 = (t0 + xt) * 128;
            int d0 = y * 128;
#pragma unroll
            for (int m = 0; m < 4; m++) {
                int r = wr * 64 + m * 16 + lr;
                unsigned short* yrow = Y + (size_t)(r0 + r) * DM + d0;
#pragma unroll
                for (int n = 0; n < 4; n++) {
                    int dc = wc * 64 + n * 16 + q * 4;
                    *(uint2*)(yrow + dc) = make_uint2(pkbf(acc[m][n][0], acc[m][n][1]),
                                                      pkbf(acc[m][n][2], acc[m][n][3]));
                }
            }
        }
        if (more) {
#pragma unroll
            for (int j = 0; j < 4; j++) { cura[j] = nxta[j]; curb[j] = nxtb[j]; }
        }
    }
}

// ---------------- combine: out[t] = p0*(Y[a0]+b2[e0]) + p1*(Y[a1]+b2[e1]) ----------------
__global__ void __launch_bounds__(256) k_combine(const unsigned short* __restrict__ Y,
                                                 const float* __restrict__ b2,
                                                 const int* __restrict__ tokpos,
                                                 const int2* __restrict__ route_e,
                                                 const float2* __restrict__ route_p,
                                                 float* __restrict__ out) {
    int gt = blockIdx.x * 256 + threadIdx.x;
    int token = gt >> 6;
    int cbase = (gt & 63) * 8;
    int2 e = route_e[token];
    float2 p = route_p[token];
    int a0 = tokpos[token * 2], a1 = tokpos[token * 2 + 1];
    s16x8 y0 = *(const s16x8*)(Y + (size_t)a0 * DM + cbase);
    s16x8 y1 = *(const s16x8*)(Y + (size_t)a1 * DM + cbase);
    const float4* bb0 = (const float4*)(b2 + e.x * DM + cbase);
    const float4* bb1 = (const float4*)(b2 + e.y * DM + cbase);
    float4 b00 = bb0[0], b01 = bb0[1];
    float4 b10 = bb1[0], b11 = bb1[1];
    float r[8];
    r[0] = p.x * (bf2f((unsigned short)y0[0]) + b00.x) + p.y * (bf2f((unsigned short)y1[0]) + b10.x);
    r[1] = p.x * (bf2f((unsigned short)y0[1]) + b00.y) + p.y * (bf2f((unsigned short)y1[1]) + b10.y);
    r[2] = p.x * (bf2f((unsigned short)y0[2]) + b00.z) + p.y * (bf2f((unsigned short)y1[2]) + b10.z);
    r[3] = p.x * (bf2f((unsigned short)y0[3]) + b00.w) + p.y * (bf2f((unsigned short)y1[3]) + b10.w);
    r[4] = p.x * (bf2f((unsigned short)y0[4]) + b01.x) + p.y * (bf2f((unsigned short)y1[4]) + b11.x);
    r[5] = p.x * (bf2f((unsigned short)y0[5]) + b01.y) + p.y * (bf2f((unsigned short)y1[5]) + b11.y);
    r[6] = p.x * (bf2f((unsigned short)y0[6]) + b01.z) + p.y * (bf2f((unsigned short)y1[6]) + b11.z);
    r[7] = p.x * (bf2f((unsigned short)y0[7]) + b01.w) + p.y * (bf2f((unsigned short)y1[7]) + b11.w);
    float* op = out + (size_t)token * DM + cbase;
    *(float4*)op       = make_float4(r[0], r[1], r[2], r[3]);
    *(float4*)(op + 4) = make_float4(r[4], r[5], r[6], r[7]);
}

// ---------------- launch ----------------
extern "C" void kernel_launch(void* const* d_in, const int* in_sizes, int n_in,
                              void* d_out, int out_size, void* d_ws, size_t ws_size,
                              hipStream_t stream) {
    const float* x       = (const float*)d_in[0];
    const int*   task_id = (const int*)d_in[1];
    const float* w1      = (const float*)d_in[2];
    const float* b1      = (const float*)d_in[3];
    const float* w2      = (const float*)d_in[4];
    const float* b2      = (const float*)d_in[5];
    const float* temb    = (const float*)d_in[6];
    const float* gw      = (const float*)d_in[7];
    const float* gb      = (const float*)d_in[8];
    float* out = (float*)d_out;

    char* ws = (char*)d_ws;
    double* bstats   = (double*)(ws + WS_BSTATS);
    double* dmean    = (double*)(ws + WS_DMEAN);
    double* drstd    = (double*)(ws + WS_DRSTD);
    double* dcolsum  = (double*)(ws + WS_DCOLSUM);
    double* dtask    = (double*)(ws + WS_DTASK);
    int*    hist     = (int*)(ws + WS_HIST);
    int*    cursor   = (int*)(ws + WS_CURSOR);
    int*    seg_off  = (int*)(ws + WS_SEGOFF);
    int2*   route_e  = (int2*)(ws + WS_ROUTE_E);
    float2* route_p  = (float2*)(ws + WS_ROUTE_P);
    int*    atok     = (int*)(ws + WS_ATOK);
    float*  aprob    = (float*)(ws + WS_APROB);
    int*    tokpos   = (int*)(ws + WS_TOKPOS);
    unsigned short* w1t = (unsigned short*)(ws + WS_W1T);
    unsigned short* w2t = (unsigned short*)(ws + WS_W2T);
    unsigned short* xb  = (unsigned short*)(ws + WS_XB);
    unsigned short* Y   = (unsigned short*)(ws + WS_Y);
    unsigned short* H   = (unsigned short*)(ws + WS_H);

    // 128-row tiles per chunk, from remaining ws
    int TPC = (int)((ws_size - (size_t)WS_H) / (size_t)(128 * DFF * 2));
    if (TPC > MAXTILES) TPC = MAXTILES;
    if (TPC < 2) TPC = 2;

    hipMemsetAsync(ws, 0, WS_HDR_END, stream);
    hipMemsetAsync(ws + WS_ATOK, 0xFF, (size_t)MAXROWS * sizeof(int), stream);

    k_transpose_bf16<<<dim3(DFF / 32, DM / 32, NE), 256, 0, stream>>>(w1, w1t, DM, DFF);
    k_transpose_bf16<<<dim3(DM / 32, DFF / 32, NE), 256, 0, stream>>>(w2, w2t, DFF, DM);

    k_xstats<<<dim3(1024, NB), 256, 0, stream>>>(x, xb, bstats);
    k_finalize<<<1, 256, 0, stream>>>(bstats, dmean, drstd, dcolsum, dtask,
                                      gw, gb, temb, task_id, out + OUT_TASK);

    k_gate<<<NTOK / 256, 256, 0, stream>>>(x, gw, dmean, drstd, dcolsum, dtask,
                                           hist, route_e, route_p, out + OUT_TOPK);
    k_offsets_lb<<<1, 64, 0, stream>>>(hist, seg_off, out + OUT_LB);
    k_scatter<<<NTOK / 256, 256, 0, stream>>>(route_e, route_p, seg_off, cursor,
                                              atok, aprob, tokpos);

    for (int t0 = 0; t0 < MAXTILES; t0 += TPC) {
        k_gemm1<<<512, 256, 0, stream>>>(xb, w1t, b1, atok, seg_off, H, t0, TPC, MAXTILES);
        k_gemm2<<<512, 256, 0, stream>>>(H, w2t, seg_off, Y, t0, TPC, MAXTILES);
    }
    k_combine<<<NTOK / 4, 256, 0, stream>>>(Y, b2, tokpos, route_e, route_p, out);
}

// Round 10
// 709.315 us; speedup vs baseline: 1.3156x; 1.3156x over previous
//
#include <hip/hip_runtime.h>

// ---------------- problem constants ----------------
#define NB      8
#define SEQ     4096
#define DM      512
#define DFF     2048
#define NE      8
#define NTOK    32768            // NB*SEQ
#define NPB     2097152          // SEQ*DM elems per batch
#define MAXROWS 66560            // 520 * 128 >= 65536 + 8*127
#define MAXTILES 520             // 128-row tiles

// output layout (fp32 elements)
#define OUT_LB   16777216
#define OUT_TOPK 16777217
#define OUT_TASK 16842753

// ws byte offsets
#define WS_BSTATS   0            // double[8][1024][2]
#define WS_DMEAN    131072
#define WS_DRSTD    131136
#define WS_DCOLSUM  131200
#define WS_DTASK    131264       // double[8][8]
#define WS_HIST     131776
#define WS_CURSOR   131808
#define WS_SEGOFF   131840
#define WS_HDR_END  131904
#define WS_ROUTE_E  131904       // int2[32768]
#define WS_ROUTE_P  394048       // float2[32768]
#define WS_ATOK     656192       // int[66560]
#define WS_APROB    922432       // float[66560]
#define WS_TOKPOS   1188672      // int[32768*2]
#define WS_W1T      1450816      // ushort[8*2048*512]
#define WS_W2T      18228032     // ushort[8*512*2048]
#define WS_XB       35005248     // ushort[32768*512]
#define WS_Y        68559680     // ushort[66560*512]
#define WS_H        136717120    // ushort[TPC*128*2048]

typedef __attribute__((ext_vector_type(4))) float  f32x4;
typedef __attribute__((ext_vector_type(8))) __bf16 bf16x8;
typedef __attribute__((ext_vector_type(8))) short  s16x8;

__device__ __forceinline__ unsigned short f2bf(float f) {
    unsigned int u = __builtin_bit_cast(unsigned int, f);
    u += 0x7FFFu + ((u >> 16) & 1u);
    return (unsigned short)(u >> 16);
}
__device__ __forceinline__ float bf2f(unsigned short b) {
    unsigned int u = ((unsigned int)b) << 16;
    return __builtin_bit_cast(float, u);
}
__device__ __forceinline__ unsigned int pkbf(float a, float b) {
    unsigned int r;
    asm("v_cvt_pk_bf16_f32 %0, %1, %2" : "=v"(r) : "v"(a), "v"(b));
    return r;
}

#define GLDS16(g, l)                                                              \
    __builtin_amdgcn_global_load_lds(                                             \
        (const __attribute__((address_space(1))) unsigned int*)(const void*)(g),  \
        (__attribute__((address_space(3))) unsigned int*)(void*)(l), 16, 0, 0)

// ---------------- weight transpose + bf16 convert ----------------
__global__ void k_transpose_bf16(const float* __restrict__ in,
                                 unsigned short* __restrict__ outT,
                                 int R, int C) {
    __shared__ float tile[32][33];
    int e = blockIdx.z;
    const float* src = in + (size_t)e * R * C;
    unsigned short* dst = outT + (size_t)e * R * C;
    int tx = threadIdx.x & 31, ty = threadIdx.x >> 5;
    int c0 = blockIdx.x * 32, r0 = blockIdx.y * 32;
#pragma unroll
    for (int i = 0; i < 4; i++) {
        int r = r0 + ty + i * 8;
        tile[ty + i * 8][tx] = src[(size_t)r * C + c0 + tx];
    }
    __syncthreads();
#pragma unroll
    for (int i = 0; i < 4; i++) {
        int rr = c0 + ty + i * 8;
        dst[(size_t)rr * R + r0 + tx] = f2bf(tile[tx][ty + i * 8]);
    }
}

// ---------------- fused: x -> bf16 copy + fp64 batch stats ----------------
__global__ void __launch_bounds__(256) k_xstats(const float* __restrict__ x,
                                                unsigned short* __restrict__ xb,
                                                double* __restrict__ bstats) {
    int b = blockIdx.y, cblk = blockIdx.x, t = threadIdx.x;
    size_t base = (size_t)b * NPB + (size_t)cblk * 2048 + (size_t)t * 8;
    float4 a = *(const float4*)(x + base);
    float4 v = *(const float4*)(x + base + 4);
    s16x8 o = {(short)f2bf(a.x), (short)f2bf(a.y), (short)f2bf(a.z), (short)f2bf(a.w),
               (short)f2bf(v.x), (short)f2bf(v.y), (short)f2bf(v.z), (short)f2bf(v.w)};
    *(s16x8*)(xb + base) = o;
    double s  = (double)a.x + (double)a.y + (double)a.z + (double)a.w
              + (double)v.x + (double)v.y + (double)v.z + (double)v.w;
    double ss = (double)a.x * a.x + (double)a.y * a.y + (double)a.z * a.z + (double)a.w * a.w
              + (double)v.x * v.x + (double)v.y * v.y + (double)v.z * v.z + (double)v.w * v.w;
    for (int o2 = 32; o2; o2 >>= 1) { s += __shfl_down(s, o2); ss += __shfl_down(ss, o2); }
    __shared__ double as_[4], ass_[4];
    int w = t >> 6;
    if ((t & 63) == 0) { as_[w] = s; ass_[w] = ss; }
    __syncthreads();
    if (t == 0) {
        s  = as_[0] + as_[1] + as_[2] + as_[3];
        ss = ass_[0] + ass_[1] + ass_[2] + ass_[3];
        bstats[(b * 1024 + cblk) * 2]     = s;
        bstats[(b * 1024 + cblk) * 2 + 1] = ss;
    }
}

// ---------------- finalize mean/rstd, gate colsum, task terms ----------------
__global__ void k_finalize(const double* __restrict__ bstats,
                           double* __restrict__ dmean, double* __restrict__ drstd,
                           double* __restrict__ dcolsum, double* __restrict__ dtask,
                           const float* __restrict__ gw, const float* __restrict__ gb,
                           const float* __restrict__ temb, const int* __restrict__ task_id,
                           float* __restrict__ out_task) {
    int t = threadIdx.x;
    int b = t >> 5, l = t & 31;
    double s = 0.0, ss = 0.0;
    for (int i = l; i < 1024; i += 32) {
        s  += bstats[(b * 1024 + i) * 2];
        ss += bstats[(b * 1024 + i) * 2 + 1];
    }
    for (int o = 16; o; o >>= 1) { s += __shfl_down(s, o, 32); ss += __shfl_down(ss, o, 32); }
    if (l == 0) {
        double N = (double)NPB;
        double m = s / N;
        double var = ss / N - m * m;
        dmean[b] = m;
        drstd[b] = 1.0 / sqrt(var + 1e-5);
    }
    __shared__ double colp[32][8];
    {
        int e = t & 7, g = t >> 3;
        double a = 0.0;
        for (int r = g * 16; r < g * 16 + 16; r++) a += (double)gw[r * 8 + e];
        colp[g][e] = a;
    }
    __syncthreads();
    if (t < 8) {
        double a = 0.0;
        for (int g = 0; g < 32; g++) a += colp[g][t];
        dcolsum[t] = a;
    }
    if (t < 64) {
        int b2 = t >> 3, e = t & 7;
        int tid = task_id[b2];
        double a = (double)gb[e];
        for (int d = 0; d < 64; d++)
            a += (double)temb[tid * 64 + d] * (double)gw[(512 + d) * 8 + e];
        dtask[t] = a;
    }
    if (t < 8) out_task[t] = (float)task_id[t];
}

// ---------------- gate: one THREAD per token (fp64, broadcast LDS reads) ----------------
__global__ void __launch_bounds__(256) k_gate(const float* __restrict__ x,
                                              const float* __restrict__ gw,
                                              const double* __restrict__ dmean,
                                              const double* __restrict__ drstd,
                                              const double* __restrict__ dcolsum,
                                              const double* __restrict__ dtask,
                                              int* __restrict__ hist,
                                              int2* __restrict__ route_e,
                                              float2* __restrict__ route_p,
                                              float* __restrict__ out_topk) {
    __shared__ float gws[DM * 8];
    __shared__ int lh[8];
    int t = threadIdx.x;
    if (t < 8) lh[t] = 0;
#pragma unroll
    for (int i = 0; i < 16; i++) gws[i * 256 + t] = gw[i * 256 + t];
    __syncthreads();

    int token = blockIdx.x * 256 + t;
    int b = token >> 12;
    const float4* xp = (const float4*)(x + (size_t)token * DM);

    double acc[8] = {0, 0, 0, 0, 0, 0, 0, 0};
#pragma unroll 2
    for (int i = 0; i < 128; i++) {
        float4 v = xp[i];
        double dx = v.x, dy = v.y, dz = v.z, dw = v.w;
        const float* g = &gws[i * 32];
#pragma unroll
        for (int e = 0; e < 8; e++)
            acc[e] += dx * (double)g[e] + dy * (double)g[8 + e]
                    + dz * (double)g[16 + e] + dw * (double)g[24 + e];
    }

    double m = dmean[b], rs = drstd[b];
    double lg[8];
#pragma unroll
    for (int e = 0; e < 8; e++) lg[e] = rs * (acc[e] - m * dcolsum[e]) + dtask[b * 8 + e];
    int i0 = 0;
#pragma unroll
    for (int e = 1; e < 8; e++) if (lg[e] > lg[i0]) i0 = e;
    int i1 = (i0 == 0) ? 1 : 0;
#pragma unroll
    for (int e = 0; e < 8; e++) if (e != i0 && lg[e] > lg[i1]) i1 = e;
    double d = exp(lg[i1] - lg[i0]);
    double p0 = 1.0 / (1.0 + d);
    double p1 = d / (1.0 + d);
    out_topk[token * 2]     = (float)i0;
    out_topk[token * 2 + 1] = (float)i1;
    atomicAdd(&lh[i0], 1);
    atomicAdd(&lh[i1], 1);
    route_e[token] = make_int2(i0, i1);
    route_p[token] = make_float2((float)p0, (float)p1);
    __syncthreads();
    if (t < 8) atomicAdd(&hist[t], lh[t]);
}

// ---------------- segment offsets (128-padded) + lb_loss ----------------
__global__ void k_offsets_lb(const int* __restrict__ hist, int* __restrict__ seg_off,
                             float* __restrict__ out_lb) {
    if (threadIdx.x == 0) {
        int off = 0;
        double ssd = 0.0;
        for (int e = 0; e < 8; e++) {
            seg_off[e] = off;
            off += (hist[e] + 127) & ~127;
            double d = (double)hist[e] - 8192.0;
            ssd += d * d;
        }
        seg_off[8] = off;
        double stdv = sqrt(ssd / 7.0);
        double m = 8192.0 + 1e-6;
        double r = stdv / m;
        *out_lb = (float)(r * r);
    }
}

// ---------------- scatter: LDS-aggregated two-level + inverse map ----------------
__global__ void __launch_bounds__(256) k_scatter(const int2* __restrict__ route_e,
                                                 const float2* __restrict__ route_p,
                                                 const int* __restrict__ seg_off,
                                                 int* __restrict__ cursor,
                                                 int* __restrict__ atok,
                                                 float* __restrict__ aprob,
                                                 int* __restrict__ tokpos) {
    __shared__ int lcount[8];
    __shared__ int lbase[8];
    int t = threadIdx.x;
    if (t < 8) lcount[t] = 0;
    __syncthreads();
    int tok = blockIdx.x * 256 + t;
    int2 e = route_e[tok];
    float2 p = route_p[tok];
    int p0 = atomicAdd(&lcount[e.x], 1);
    int p1 = atomicAdd(&lcount[e.y], 1);
    __syncthreads();
    if (t < 8) lbase[t] = atomicAdd(&cursor[t], lcount[t]);
    __syncthreads();
    int a0 = seg_off[e.x] + lbase[e.x] + p0;
    atok[a0] = tok; aprob[a0] = p.x;
    int a1 = seg_off[e.y] + lbase[e.y] + p1;
    atok[a1] = tok; aprob[a1] = p.y;
    tokpos[tok * 2]     = a0;
    tokpos[tok * 2 + 1] = a1;
}

// ============ 128x128 MFMA GEMMs: 3-slot-A / 2-slot-B deep prefetch ============
// LDS: As[3][128][64] (48 KB) + Bs[2][128][64] (32 KB) = 80 KB -> 2 blocks/CU.
// A staged 2 K-tiles ahead (covers gather latency), B 1 ahead (L2-hot weights).
// Issue order per iter: B(it+1) then A(it+2). Steady-state wait vmcnt(12)
// drains exactly {A(it), B(it)}; tail vmcnt(8)/vmcnt(0). XOR swizzle c^=(row&7).
// mfma(bfv, af): lane's 4 acc elems = 4 consecutive OUTPUT COLUMNS.

#define STAGE_B4(UB, KOF, LOF)                                      \
    _Pragma("unroll")                                               \
    for (int j_ = 0; j_ < 4; j_++) GLDS16(UB[j_] + (KOF), bdst[j_] + (LOF));
#define STAGE_A4(UA, KOF, LOF)                                      \
    _Pragma("unroll")                                               \
    for (int j_ = 0; j_ < 4; j_++) GLDS16(UA[j_] + (KOF), adst[j_] + (LOF));

#define COMPUTE_TILE(ASLOT, BSLOT)                                                 \
    {                                                                              \
        const unsigned short* Ab = &As[(ASLOT) * 8192];                            \
        const unsigned short* Bb = &Bs[(BSLOT) * 8192];                            \
        __builtin_amdgcn_s_setprio(1);                                             \
        _Pragma("unroll")                                                          \
        for (int h = 0; h < 2; h++) {                                              \
            bf16x8 af[4], bfv[4];                                                  \
            _Pragma("unroll")                                                      \
            for (int m = 0; m < 4; m++) {                                          \
                int R = wr * 64 + m * 16 + lr;                                     \
                af[m] = *(const bf16x8*)&Ab[R * 64 + (((h << 2) + q) ^ (R & 7)) * 8]; \
            }                                                                      \
            _Pragma("unroll")                                                      \
            for (int n = 0; n < 4; n++) {                                          \
                int R = wc * 64 + n * 16 + lr;                                     \
                bfv[n] = *(const bf16x8*)&Bb[R * 64 + (((h << 2) + q) ^ (R & 7)) * 8]; \
            }                                                                      \
            _Pragma("unroll")                                                      \
            for (int m = 0; m < 4; m++)                                            \
                _Pragma("unroll")                                                  \
                for (int n = 0; n < 4; n++)                                        \
                    acc[m][n] = __builtin_amdgcn_mfma_f32_16x16x32_bf16(bfv[n], af[m], acc[m][n], 0, 0, 0); \
        }                                                                          \
        __builtin_amdgcn_s_setprio(0);                                             \
    }

#define KLOOP(NK)                                                                  \
    /* prologue: B(0), A(0), A(1) */                                               \
    STAGE_B4(curb, 0, 0);                                                          \
    STAGE_A4(cura, 0, 0);                                                          \
    STAGE_A4(cura, 64, 8192);                                                      \
    {                                                                              \
        int cA = 0;                                                                \
        for (int it = 0; it < (NK); ++it) {                                        \
            int sA = cA + 2; if (sA >= 3) sA -= 3;                                 \
            if (it + 1 < (NK)) { STAGE_B4(curb, (it + 1) * 64, ((it + 1) & 1) * 8192); } \
            if (it + 2 < (NK)) { STAGE_A4(cura, (it + 2) * 64, sA * 8192); }       \
            if (it + 2 < (NK))      asm volatile("s_waitcnt vmcnt(12)" ::: "memory"); \
            else if (it + 1 < (NK)) asm volatile("s_waitcnt vmcnt(8)" ::: "memory");  \
            else                    asm volatile("s_waitcnt vmcnt(0)" ::: "memory");  \
            __builtin_amdgcn_s_barrier();                                          \
            __builtin_amdgcn_sched_barrier(0);                                     \
            COMPUTE_TILE(cA, it & 1);                                              \
            __builtin_amdgcn_sched_barrier(0);                                     \
            asm volatile("" ::: "memory");                                         \
            __builtin_amdgcn_s_barrier();                                          \
            cA = (cA + 1 == 3) ? 0 : cA + 1;                                       \
        }                                                                          \
    }

// ---------------- GEMM1: H[chunk] = silu(X_gather @ w1[e] + b1[e]) ----------------
__global__ void __launch_bounds__(256) k_gemm1(const unsigned short* __restrict__ xb,
                                               const unsigned short* __restrict__ w1t,
                                               const float* __restrict__ b1,
                                               const int* __restrict__ atok,
                                               const int* __restrict__ seg_off,
                                               unsigned short* __restrict__ H,
                                               int t0) {
    int nwg = (int)gridDim.x;                       // TPC*16, multiple of 8
    int bid = (int)blockIdx.x;
    int wg = (bid & 7) * (nwg >> 3) + (bid >> 3);   // XCD-chunked logical id
    int xt = wg >> 4, y = wg & 15;                  // NY = 16
    int r0 = (t0 + xt) * 128;
    if (r0 >= seg_off[8]) return;
    int e = 0;
    while (seg_off[e + 1] <= r0) e++;
    int f0 = y * 128;

    int tid = threadIdx.x;
    int w = tid >> 6, l = tid & 63;
    int c = l & 7;
    int wr = w >> 1, wc = w & 1, lr = l & 15, q = l >> 4;

    __shared__ __align__(16) unsigned short As[3 * 128 * 64];
    __shared__ __align__(16) unsigned short Bs[2 * 128 * 64];

    const unsigned short* cura[4];
    const unsigned short* curb[4];
    unsigned short*       adst[4];
    unsigned short*       bdst[4];
#pragma unroll
    for (int j = 0; j < 4; j++) {
        int row = w * 32 + j * 8 + (l >> 3);
        int cs = c ^ (row & 7);
        int tok = atok[r0 + row]; if (tok < 0) tok = 0;
        cura[j] = xb + (size_t)tok * DM + cs * 8;
        curb[j] = w1t + ((size_t)e * DFF + f0 + row) * DM + cs * 8;
        adst[j] = &As[(w * 32 + j * 8) * 64];
        bdst[j] = &Bs[(w * 32 + j * 8) * 64];
    }

    f32x4 acc[4][4] = {};
    KLOOP(8)                                        // K = DM = 512

    // epilogue: acc[m][n][j] -> H row (wr*64+m*16+lr), col f0 + wc*64+n*16+q*4+j
    const float* b1e = b1 + e * DFF + f0;
#pragma unroll
    for (int m = 0; m < 4; m++) {
        int r = wr * 64 + m * 16 + lr;
        unsigned short* hrow = H + ((size_t)xt * 128 + r) * DFF + f0;
#pragma unroll
        for (int n = 0; n < 4; n++) {
            int fc = wc * 64 + n * 16 + q * 4;
            float4 bias = *(const float4*)(b1e + fc);
            float v0 = acc[m][n][0] + bias.x; v0 = v0 / (1.0f + __expf(-v0));
            float v1 = acc[m][n][1] + bias.y; v1 = v1 / (1.0f + __expf(-v1));
            float v2 = acc[m][n][2] + bias.z; v2 = v2 / (1.0f + __expf(-v2));
            float v3 = acc[m][n][3] + bias.w; v3 = v3 / (1.0f + __expf(-v3));
            *(uint2*)(hrow + fc) = make_uint2(pkbf(v0, v1), pkbf(v2, v3));
        }
    }
}

// ---------------- GEMM2: Y[aidx] = H[chunk] @ w2[e]  (K=2048) ----------------
__global__ void __launch_bounds__(256) k_gemm2(const unsigned short* __restrict__ H,
                                               const unsigned short* __restrict__ w2t,
                                               const int* __restrict__ seg_off,
                                               unsigned short* __restrict__ Y,
                                               int t0) {
    int nwg = (int)gridDim.x;                       // TPC*4, TPC even -> %8==0
    int bid = (int)blockIdx.x;
    int wg = (bid & 7) * (nwg >> 3) + (bid >> 3);
    int xt = wg >> 2, y = wg & 3;                   // NY = 4
    int r0 = (t0 + xt) * 128;
    if (r0 >= seg_off[8]) return;
    int e = 0;
    while (seg_off[e + 1] <= r0) e++;
    int d0 = y * 128;

    int tid = threadIdx.x;
    int w = tid >> 6, l = tid & 63;
    int c = l & 7;
    int wr = w >> 1, wc = w & 1, lr = l & 15, q = l >> 4;

    __shared__ __align__(16) unsigned short As[3 * 128 * 64];
    __shared__ __align__(16) unsigned short Bs[2 * 128 * 64];

    const unsigned short* cura[4];
    const unsigned short* curb[4];
    unsigned short*       adst[4];
    unsigned short*       bdst[4];
#pragma unroll
    for (int j = 0; j < 4; j++) {
        int row = w * 32 + j * 8 + (l >> 3);
        int cs = c ^ (row & 7);
        cura[j] = H + ((size_t)xt * 128 + row) * DFF + cs * 8;
        curb[j] = w2t + ((size_t)e * DM + d0 + row) * DFF + cs * 8;
        adst[j] = &As[(w * 32 + j * 8) * 64];
        bdst[j] = &Bs[(w * 32 + j * 8) * 64];
    }

    f32x4 acc[4][4] = {};
    KLOOP(32)                                       // K = DFF = 2048

    // epilogue: acc[m][n][j] -> Y row (wr*64+m*16+lr), col d0 + wc*64+n*16+q*4+j
#pragma unroll
    for (int m = 0; m < 4; m++) {
        int r = wr * 64 + m * 16 + lr;
        unsigned short* yrow = Y + (size_t)(r0 + r) * DM + d0;
#pragma unroll
        for (int n = 0; n < 4; n++) {
            int dc = wc * 64 + n * 16 + q * 4;
            *(uint2*)(yrow + dc) = make_uint2(pkbf(acc[m][n][0], acc[m][n][1]),
                                              pkbf(acc[m][n][2], acc[m][n][3]));
        }
    }
}

// ---------------- combine: out[t] = p0*(Y[a0]+b2[e0]) + p1*(Y[a1]+b2[e1]) ----------------
__global__ void __launch_bounds__(256) k_combine(const unsigned short* __restrict__ Y,
                                                 const float* __restrict__ b2,
                                                 const int* __restrict__ tokpos,
                                                 const int2* __restrict__ route_e,
                                                 const float2* __restrict__ route_p,
                                                 float* __restrict__ out) {
    int gt = blockIdx.x * 256 + threadIdx.x;
    int token = gt >> 6;
    int cbase = (gt & 63) * 8;
    int2 e = route_e[token];
    float2 p = route_p[token];
    int a0 = tokpos[token * 2], a1 = tokpos[token * 2 + 1];
    s16x8 y0 = *(const s16x8*)(Y + (size_t)a0 * DM + cbase);
    s16x8 y1 = *(const s16x8*)(Y + (size_t)a1 * DM + cbase);
    const float4* bb0 = (const float4*)(b2 + e.x * DM + cbase);
    const float4* bb1 = (const float4*)(b2 + e.y * DM + cbase);
    float4 b00 = bb0[0], b01 = bb0[1];
    float4 b10 = bb1[0], b11 = bb1[1];
    float r[8];
    r[0] = p.x * (bf2f((unsigned short)y0[0]) + b00.x) + p.y * (bf2f((unsigned short)y1[0]) + b10.x);
    r[1] = p.x * (bf2f((unsigned short)y0[1]) + b00.y) + p.y * (bf2f((unsigned short)y1[1]) + b10.y);
    r[2] = p.x * (bf2f((unsigned short)y0[2]) + b00.z) + p.y * (bf2f((unsigned short)y1[2]) + b10.z);
    r[3] = p.x * (bf2f((unsigned short)y0[3]) + b00.w) + p.y * (bf2f((unsigned short)y1[3]) + b10.w);
    r[4] = p.x * (bf2f((unsigned short)y0[4]) + b01.x) + p.y * (bf2f((unsigned short)y1[4]) + b11.x);
    r[5] = p.x * (bf2f((unsigned short)y0[5]) + b01.y) + p.y * (bf2f((unsigned short)y1[5]) + b11.y);
    r[6] = p.x * (bf2f((unsigned short)y0[6]) + b01.z) + p.y * (bf2f((unsigned short)y1[6]) + b11.z);
    r[7] = p.x * (bf2f((unsigned short)y0[7]) + b01.w) + p.y * (bf2f((unsigned short)y1[7]) + b11.w);
    float* op = out + (size_t)token * DM + cbase;
    *(float4*)op       = make_float4(r[0], r[1], r[2], r[3]);
    *(float4*)(op + 4) = make_float4(r[4], r[5], r[6], r[7]);
}

// ---------------- launch ----------------
extern "C" void kernel_launch(void* const* d_in, const int* in_sizes, int n_in,
                              void* d_out, int out_size, void* d_ws, size_t ws_size,
                              hipStream_t stream) {
    const float* x       = (const float*)d_in[0];
    const int*   task_id = (const int*)d_in[1];
    const float* w1      = (const float*)d_in[2];
    const float* b1      = (const float*)d_in[3];
    const float* w2      = (const float*)d_in[4];
    const float* b2      = (const float*)d_in[5];
    const float* temb    = (const float*)d_in[6];
    const float* gw      = (const float*)d_in[7];
    const float* gb      = (const float*)d_in[8];
    float* out = (float*)d_out;

    char* ws = (char*)d_ws;
    double* bstats   = (double*)(ws + WS_BSTATS);
    double* dmean    = (double*)(ws + WS_DMEAN);
    double* drstd    = (double*)(ws + WS_DRSTD);
    double* dcolsum  = (double*)(ws + WS_DCOLSUM);
    double* dtask    = (double*)(ws + WS_DTASK);
    int*    hist     = (int*)(ws + WS_HIST);
    int*    cursor   = (int*)(ws + WS_CURSOR);
    int*    seg_off  = (int*)(ws + WS_SEGOFF);
    int2*   route_e  = (int2*)(ws + WS_ROUTE_E);
    float2* route_p  = (float2*)(ws + WS_ROUTE_P);
    int*    atok     = (int*)(ws + WS_ATOK);
    float*  aprob    = (float*)(ws + WS_APROB);
    int*    tokpos   = (int*)(ws + WS_TOKPOS);
    unsigned short* w1t = (unsigned short*)(ws + WS_W1T);
    unsigned short* w2t = (unsigned short*)(ws + WS_W2T);
    unsigned short* xb  = (unsigned short*)(ws + WS_XB);
    unsigned short* Y   = (unsigned short*)(ws + WS_Y);
    unsigned short* H   = (unsigned short*)(ws + WS_H);

    // 128-row tiles per chunk, from remaining ws; even for grid%8
    int TPC = (int)((ws_size - (size_t)WS_H) / (size_t)(128 * DFF * 2));
    if (TPC > MAXTILES) TPC = MAXTILES;
    TPC &= ~1;
    if (TPC < 2) TPC = 2;

    hipMemsetAsync(ws, 0, WS_HDR_END, stream);
    hipMemsetAsync(ws + WS_ATOK, 0xFF, (size_t)MAXROWS * sizeof(int), stream);

    k_transpose_bf16<<<dim3(DFF / 32, DM / 32, NE), 256, 0, stream>>>(w1, w1t, DM, DFF);
    k_transpose_bf16<<<dim3(DM / 32, DFF / 32, NE), 256, 0, stream>>>(w2, w2t, DFF, DM);

    k_xstats<<<dim3(1024, NB), 256, 0, stream>>>(x, xb, bstats);
    k_finalize<<<1, 256, 0, stream>>>(bstats, dmean, drstd, dcolsum, dtask,
                                      gw, gb, temb, task_id, out + OUT_TASK);

    k_gate<<<NTOK / 256, 256, 0, stream>>>(x, gw, dmean, drstd, dcolsum, dtask,
                                           hist, route_e, route_p, out + OUT_TOPK);
    k_offsets_lb<<<1, 64, 0, stream>>>(hist, seg_off, out + OUT_LB);
    k_scatter<<<NTOK / 256, 256, 0, stream>>>(route_e, route_p, seg_off, cursor,
                                              atok, aprob, tokpos);

    for (int t0 = 0; t0 < MAXTILES; t0 += TPC) {
        k_gemm1<<<TPC * 16, 256, 0, stream>>>(xb, w1t, b1, atok, seg_off, H, t0);
        k_gemm2<<<TPC * 4, 256, 0, stream>>>(H, w2t, seg_off, Y, t0);
    }
    k_combine<<<NTOK / 4, 256, 0, stream>>>(Y, b2, tokpos, route_e, route_p, out);
}

// Round 11
// 565.002 us; speedup vs baseline: 1.6517x; 1.2554x over previous
//
#include <hip/hip_runtime.h>

// ---------------- problem constants ----------------
#define NB      8
#define SEQ     4096
#define DM      512
#define DFF     2048
#define NE      8
#define NTOK    32768            // NB*SEQ
#define NPB     2097152          // SEQ*DM elems per batch
#define MAXROWS 66560            // 520 * 128 >= 65536 + 8*127
#define MAXTILES 520             // 128-row tiles

// output layout (fp32 elements)
#define OUT_LB   16777216
#define OUT_TOPK 16777217
#define OUT_TASK 16842753

// ws byte offsets
#define WS_BSTATS   0            // double[128][2] (per xgate block)
#define WS_DMEAN    2048
#define WS_DRSTD    2112
#define WS_DCOLSUM  2176
#define WS_DTASK    2240         // double[8][8]
#define WS_HIST     2752
#define WS_CURSOR   2784
#define WS_SEGOFF   2816
#define WS_HDR_END  2944
#define WS_ROUTE_E  2944         // int2[32768]
#define WS_ROUTE_P  265088       // float2[32768]
#define WS_ATOK     527232       // int[66560]
#define WS_APROB    793472       // float[66560]
#define WS_TOKPOS   1059712      // int[32768*2]
#define WS_RAW      1321856      // double[32768][8]
#define WS_W1T      3419008      // ushort[8*2048*512]
#define WS_W2T      20196224     // ushort[8*512*2048]
#define WS_XB       36973440     // ushort[32768*512]
#define WS_Y        70527872     // ushort[66560*512]
#define WS_H        138685312    // ushort[TPC*128*2048]

typedef __attribute__((ext_vector_type(4))) float  f32x4;
typedef __attribute__((ext_vector_type(8))) __bf16 bf16x8;
typedef __attribute__((ext_vector_type(8))) short  s16x8;

__device__ __forceinline__ unsigned short f2bf(float f) {
    unsigned int u = __builtin_bit_cast(unsigned int, f);
    u += 0x7FFFu + ((u >> 16) & 1u);
    return (unsigned short)(u >> 16);
}
__device__ __forceinline__ float bf2f(unsigned short b) {
    unsigned int u = ((unsigned int)b) << 16;
    return __builtin_bit_cast(float, u);
}
__device__ __forceinline__ unsigned int pkbf(float a, float b) {
    unsigned int r;
    asm("v_cvt_pk_bf16_f32 %0, %1, %2" : "=v"(r) : "v"(a), "v"(b));
    return r;
}

#define GLDS16(g, l)                                                              \
    __builtin_amdgcn_global_load_lds(                                             \
        (const __attribute__((address_space(1))) unsigned int*)(const void*)(g),  \
        (__attribute__((address_space(3))) unsigned int*)(void*)(l), 16, 0, 0)

// ---------------- weight transpose + bf16 convert ----------------
__global__ void k_transpose_bf16(const float* __restrict__ in,
                                 unsigned short* __restrict__ outT,
                                 int R, int C) {
    __shared__ float tile[32][33];
    int e = blockIdx.z;
    const float* src = in + (size_t)e * R * C;
    unsigned short* dst = outT + (size_t)e * R * C;
    int tx = threadIdx.x & 31, ty = threadIdx.x >> 5;
    int c0 = blockIdx.x * 32, r0 = blockIdx.y * 32;
#pragma unroll
    for (int i = 0; i < 4; i++) {
        int r = r0 + ty + i * 8;
        tile[ty + i * 8][tx] = src[(size_t)r * C + c0 + tx];
    }
    __syncthreads();
#pragma unroll
    for (int i = 0; i < 4; i++) {
        int rr = c0 + ty + i * 8;
        dst[(size_t)rr * R + r0 + tx] = f2bf(tile[tx][ty + i * 8]);
    }
}

// ---------------- fused: gate raw logits (fp64) + x->bf16 + batch stats ----------------
// One THREAD per token; gate_w rows 0..511 in LDS, read at wave-uniform addrs
// (pure broadcast). Same fp64 MAC expression/order as the previously-passing gate.
__global__ void __launch_bounds__(256) k_xgate(const float* __restrict__ x,
                                               const float* __restrict__ gw,
                                               unsigned short* __restrict__ xb,
                                               double* __restrict__ bstats,
                                               double* __restrict__ raw) {
    __shared__ float gws[DM * 8];    // 16 KB
    int t = threadIdx.x;
#pragma unroll
    for (int i = 0; i < 16; i++) gws[i * 256 + t] = gw[i * 256 + t];
    __syncthreads();

    int token = blockIdx.x * 256 + t;
    const float4* xp = (const float4*)(x + (size_t)token * DM);
    unsigned short* xbp = xb + (size_t)token * DM;

    double acc[8] = {0, 0, 0, 0, 0, 0, 0, 0};
    double s = 0.0, ss = 0.0;
#pragma unroll 2
    for (int i = 0; i < 128; i += 2) {
        float4 v0 = xp[i];
        float4 v1 = xp[i + 1];
        {
            double dx = v0.x, dy = v0.y, dz = v0.z, dw = v0.w;
            const float* g = &gws[i * 32];
#pragma unroll
            for (int e = 0; e < 8; e++)
                acc[e] += dx * (double)g[e] + dy * (double)g[8 + e]
                        + dz * (double)g[16 + e] + dw * (double)g[24 + e];
            s  += dx + dy + dz + dw;
            ss += dx * dx + dy * dy + dz * dz + dw * dw;
        }
        {
            double dx = v1.x, dy = v1.y, dz = v1.z, dw = v1.w;
            const float* g = &gws[(i + 1) * 32];
#pragma unroll
            for (int e = 0; e < 8; e++)
                acc[e] += dx * (double)g[e] + dy * (double)g[8 + e]
                        + dz * (double)g[16 + e] + dw * (double)g[24 + e];
            s  += dx + dy + dz + dw;
            ss += dx * dx + dy * dy + dz * dz + dw * dw;
        }
        s16x8 o = {(short)f2bf(v0.x), (short)f2bf(v0.y), (short)f2bf(v0.z), (short)f2bf(v0.w),
                   (short)f2bf(v1.x), (short)f2bf(v1.y), (short)f2bf(v1.z), (short)f2bf(v1.w)};
        *(s16x8*)(xbp + i * 4) = o;
    }
#pragma unroll
    for (int e = 0; e < 8; e++) raw[(size_t)token * 8 + e] = acc[e];

    // block stats reduction (fp64)
    for (int o = 32; o; o >>= 1) { s += __shfl_down(s, o); ss += __shfl_down(ss, o); }
    __shared__ double as_[4], ass_[4];
    int w = t >> 6;
    if ((t & 63) == 0) { as_[w] = s; ass_[w] = ss; }
    __syncthreads();
    if (t == 0) {
        s  = as_[0] + as_[1] + as_[2] + as_[3];
        ss = ass_[0] + ass_[1] + ass_[2] + ass_[3];
        bstats[blockIdx.x * 2]     = s;
        bstats[blockIdx.x * 2 + 1] = ss;
    }
}

// ---------------- finalize mean/rstd, gate colsum, task terms ----------------
__global__ void k_finalize(const double* __restrict__ bstats,
                           double* __restrict__ dmean, double* __restrict__ drstd,
                           double* __restrict__ dcolsum, double* __restrict__ dtask,
                           const float* __restrict__ gw, const float* __restrict__ gb,
                           const float* __restrict__ temb, const int* __restrict__ task_id,
                           float* __restrict__ out_task) {
    int t = threadIdx.x;
    if (t < 8) {
        double s = 0.0, ss = 0.0;
        for (int i = 0; i < 16; i++) {          // 16 xgate blocks per batch
            s  += bstats[(t * 16 + i) * 2];
            ss += bstats[(t * 16 + i) * 2 + 1];
        }
        double N = (double)NPB;
        double m = s / N;
        double var = ss / N - m * m;
        dmean[t] = m;
        drstd[t] = 1.0 / sqrt(var + 1e-5);
    }
    __shared__ double colp[32][8];
    {
        int e = t & 7, g = t >> 3;
        double a = 0.0;
        for (int r = g * 16; r < g * 16 + 16; r++) a += (double)gw[r * 8 + e];
        colp[g][e] = a;
    }
    __syncthreads();
    if (t < 8) {
        double a = 0.0;
        for (int g = 0; g < 32; g++) a += colp[g][t];
        dcolsum[t] = a;
    }
    if (t < 64) {
        int b2 = t >> 3, e = t & 7;
        int tid = task_id[b2];
        double a = (double)gb[e];
        for (int d = 0; d < 64; d++)
            a += (double)temb[tid * 64 + d] * (double)gw[(512 + d) * 8 + e];
        dtask[t] = a;
    }
    if (t < 8) out_task[t] = (float)task_id[t];
}

// ---------------- top-2 from raw logits ----------------
__global__ void __launch_bounds__(256) k_topk(const double* __restrict__ raw,
                                              const double* __restrict__ dmean,
                                              const double* __restrict__ drstd,
                                              const double* __restrict__ dcolsum,
                                              const double* __restrict__ dtask,
                                              int* __restrict__ hist,
                                              int2* __restrict__ route_e,
                                              float2* __restrict__ route_p,
                                              float* __restrict__ out_topk) {
    __shared__ int lh[8];
    int t = threadIdx.x;
    if (t < 8) lh[t] = 0;
    __syncthreads();
    int token = blockIdx.x * 256 + t;
    int b = token >> 12;
    double m = dmean[b], rs = drstd[b];
    double lg[8];
#pragma unroll
    for (int e = 0; e < 8; e++)
        lg[e] = rs * (raw[(size_t)token * 8 + e] - m * dcolsum[e]) + dtask[b * 8 + e];
    int i0 = 0;
#pragma unroll
    for (int e = 1; e < 8; e++) if (lg[e] > lg[i0]) i0 = e;
    int i1 = (i0 == 0) ? 1 : 0;
#pragma unroll
    for (int e = 0; e < 8; e++) if (e != i0 && lg[e] > lg[i1]) i1 = e;
    double d = exp(lg[i1] - lg[i0]);
    double p0 = 1.0 / (1.0 + d);
    double p1 = d / (1.0 + d);
    out_topk[token * 2]     = (float)i0;
    out_topk[token * 2 + 1] = (float)i1;
    atomicAdd(&lh[i0], 1);
    atomicAdd(&lh[i1], 1);
    route_e[token] = make_int2(i0, i1);
    route_p[token] = make_float2((float)p0, (float)p1);
    __syncthreads();
    if (t < 8) atomicAdd(&hist[t], lh[t]);
}

// ---------------- segment offsets (128-padded) + lb_loss ----------------
__global__ void k_offsets_lb(const int* __restrict__ hist, int* __restrict__ seg_off,
                             float* __restrict__ out_lb) {
    if (threadIdx.x == 0) {
        int off = 0;
        double ssd = 0.0;
        for (int e = 0; e < 8; e++) {
            seg_off[e] = off;
            off += (hist[e] + 127) & ~127;
            double d = (double)hist[e] - 8192.0;
            ssd += d * d;
        }
        seg_off[8] = off;
        double stdv = sqrt(ssd / 7.0);
        double m = 8192.0 + 1e-6;
        double r = stdv / m;
        *out_lb = (float)(r * r);
    }
}

// ---------------- scatter: LDS-aggregated two-level + inverse map ----------------
__global__ void __launch_bounds__(256) k_scatter(const int2* __restrict__ route_e,
                                                 const float2* __restrict__ route_p,
                                                 const int* __restrict__ seg_off,
                                                 int* __restrict__ cursor,
                                                 int* __restrict__ atok,
                                                 float* __restrict__ aprob,
                                                 int* __restrict__ tokpos) {
    __shared__ int lcount[8];
    __shared__ int lbase[8];
    int t = threadIdx.x;
    if (t < 8) lcount[t] = 0;
    __syncthreads();
    int tok = blockIdx.x * 256 + t;
    int2 e = route_e[tok];
    float2 p = route_p[tok];
    int p0 = atomicAdd(&lcount[e.x], 1);
    int p1 = atomicAdd(&lcount[e.y], 1);
    __syncthreads();
    if (t < 8) lbase[t] = atomicAdd(&cursor[t], lcount[t]);
    __syncthreads();
    int a0 = seg_off[e.x] + lbase[e.x] + p0;
    atok[a0] = tok; aprob[a0] = p.x;
    int a1 = seg_off[e.y] + lbase[e.y] + p1;
    atok[a1] = tok; aprob[a1] = p.y;
    tokpos[tok * 2]     = a0;
    tokpos[tok * 2 + 1] = a1;
}

// ============ MFMA GEMMs: r7-proven 2-phase double-buffered pipeline ============
// LDS: As[2]/Bs[2], XOR-swizzled [128][64] tiles staged via global_load_lds(16B).
// Per iter: issue next-tile stage -> s_waitcnt vmcnt(8) (counted; prefetch stays
// in flight) -> s_barrier -> ds_read+MFMA (setprio 1) -> s_barrier -> flip.
// mfma(bfv, af): lane's 4 acc elems = 4 consecutive OUTPUT COLUMNS.

// ---------------- GEMM1: H[chunk] = silu(X_gather @ w1[e] + b1[e]), full DFF ----------------
__global__ void __launch_bounds__(256) k_gemm1(const unsigned short* __restrict__ xb,
                                               const unsigned short* __restrict__ w1t,
                                               const float* __restrict__ b1,
                                               const int* __restrict__ atok,
                                               const int* __restrict__ seg_off,
                                               unsigned short* __restrict__ H,
                                               int t0) {
    int nwg = (int)gridDim.x;                       // TPC*16, multiple of 8
    int bid = (int)blockIdx.x;
    int wg = (bid & 7) * (nwg >> 3) + (bid >> 3);   // XCD-chunked logical id
    int xt = wg >> 4, y = wg & 15;                  // NY = 16
    int r0 = (t0 + xt) * 128;
    if (r0 >= seg_off[8]) return;
    int e = 0;
    while (seg_off[e + 1] <= r0) e++;
    int f0 = y * 128;

    int tid = threadIdx.x;
    int w = tid >> 6, l = tid & 63;
    int c = l & 7;

    __shared__ __align__(16) unsigned short As[2][128 * 64];
    __shared__ __align__(16) unsigned short Bs[2][128 * 64];

    const unsigned short* asrc[4];
    const unsigned short* bsrc[4];
    unsigned short*       adst[4];
    unsigned short*       bdst[4];
#pragma unroll
    for (int j = 0; j < 4; j++) {
        int R = w * 32 + j * 8 + (l >> 3);
        int cs = c ^ (R & 7);
        int tok = atok[r0 + R]; if (tok < 0) tok = 0;
        asrc[j] = xb + (size_t)tok * DM + cs * 8;
        bsrc[j] = w1t + ((size_t)e * DFF + f0 + R) * DM + cs * 8;
        adst[j] = &As[0][(size_t)(w * 32 + j * 8) * 64];
        bdst[j] = &Bs[0][(size_t)(w * 32 + j * 8) * 64];
    }

    f32x4 acc[4][4] = {};
    int wr = w >> 1, wc = w & 1, lr = l & 15, q = l >> 4;

    // prologue: stage k-step 0 into buffer 0
#pragma unroll
    for (int j = 0; j < 4; j++) { GLDS16(asrc[j], adst[j]); GLDS16(bsrc[j], bdst[j]); }

    int cur = 0;
    for (int it = 0; it < DM / 64; ++it) {          // 8 K-steps
        if (it + 1 < DM / 64) {
            int kn = (it + 1) * 64;
            int off = (cur ^ 1) * 128 * 64;
#pragma unroll
            for (int j = 0; j < 4; j++) {
                GLDS16(asrc[j] + kn, adst[j] + off);
                GLDS16(bsrc[j] + kn, bdst[j] + off);
            }
            asm volatile("s_waitcnt vmcnt(8)" ::: "memory");
        } else {
            asm volatile("s_waitcnt vmcnt(0)" ::: "memory");
        }
        __builtin_amdgcn_s_barrier();
        __builtin_amdgcn_sched_barrier(0);
        __builtin_amdgcn_s_setprio(1);
        const unsigned short* Ab = &As[cur][0];
        const unsigned short* Bb = &Bs[cur][0];
#pragma unroll
        for (int h = 0; h < 2; h++) {
            bf16x8 af[4], bfv[4];
#pragma unroll
            for (int m = 0; m < 4; m++) {
                int R = wr * 64 + m * 16 + lr;
                af[m] = *(const bf16x8*)&Ab[R * 64 + (((h << 2) + q) ^ (R & 7)) * 8];
            }
#pragma unroll
            for (int n = 0; n < 4; n++) {
                int R = wc * 64 + n * 16 + lr;
                bfv[n] = *(const bf16x8*)&Bb[R * 64 + (((h << 2) + q) ^ (R & 7)) * 8];
            }
#pragma unroll
            for (int m = 0; m < 4; m++)
#pragma unroll
                for (int n = 0; n < 4; n++)
                    acc[m][n] = __builtin_amdgcn_mfma_f32_16x16x32_bf16(bfv[n], af[m], acc[m][n], 0, 0, 0);
        }
        __builtin_amdgcn_s_setprio(0);
        __builtin_amdgcn_sched_barrier(0);
        asm volatile("" ::: "memory");
        __builtin_amdgcn_s_barrier();
        cur ^= 1;
    }

    // epilogue: acc[m][n][j] = H[r = wr*64+m*16+lr][f = f0 + wc*64 + n*16 + q*4 + j]
    const float* b1e = b1 + e * DFF + f0;
#pragma unroll
    for (int m = 0; m < 4; m++) {
        int r = wr * 64 + m * 16 + lr;
        unsigned short* hrow = H + ((size_t)xt * 128 + r) * DFF + f0;
#pragma unroll
        for (int n = 0; n < 4; n++) {
            int fc = wc * 64 + n * 16 + q * 4;
            float4 bias = *(const float4*)(b1e + fc);
            float v0 = acc[m][n][0] + bias.x; v0 = v0 / (1.0f + __expf(-v0));
            float v1 = acc[m][n][1] + bias.y; v1 = v1 / (1.0f + __expf(-v1));
            float v2 = acc[m][n][2] + bias.z; v2 = v2 / (1.0f + __expf(-v2));
            float v3 = acc[m][n][3] + bias.w; v3 = v3 / (1.0f + __expf(-v3));
            *(uint2*)(hrow + fc) = make_uint2(pkbf(v0, v1), pkbf(v2, v3));
        }
    }
}

// ---------------- GEMM2: Y[aidx] = H[chunk] @ w2[e]  (K=2048, plain bf16 stores) ----------------
__global__ void __launch_bounds__(256) k_gemm2(const unsigned short* __restrict__ H,
                                               const unsigned short* __restrict__ w2t,
                                               const int* __restrict__ seg_off,
                                               unsigned short* __restrict__ Y,
                                               int t0) {
    int nwg = (int)gridDim.x;                       // TPC*4, TPC even -> %8==0
    int bid = (int)blockIdx.x;
    int wg = (bid & 7) * (nwg >> 3) + (bid >> 3);
    int xt = wg >> 2, y = wg & 3;                   // NY = 4
    int r0 = (t0 + xt) * 128;
    if (r0 >= seg_off[8]) return;
    int e = 0;
    while (seg_off[e + 1] <= r0) e++;
    int d0 = y * 128;

    int tid = threadIdx.x;
    int w = tid >> 6, l = tid & 63;
    int c = l & 7;

    __shared__ __align__(16) unsigned short As[2][128 * 64];
    __shared__ __align__(16) unsigned short Bs[2][128 * 64];

    const unsigned short* asrc[4];
    const unsigned short* bsrc[4];
    unsigned short*       adst[4];
    unsigned short*       bdst[4];
#pragma unroll
    for (int j = 0; j < 4; j++) {
        int R = w * 32 + j * 8 + (l >> 3);
        int cs = c ^ (R & 7);
        asrc[j] = H + ((size_t)xt * 128 + R) * DFF + cs * 8;
        bsrc[j] = w2t + ((size_t)e * DM + d0 + R) * DFF + cs * 8;
        adst[j] = &As[0][(size_t)(w * 32 + j * 8) * 64];
        bdst[j] = &Bs[0][(size_t)(w * 32 + j * 8) * 64];
    }

    f32x4 acc[4][4] = {};
    int wr = w >> 1, wc = w & 1, lr = l & 15, q = l >> 4;

    // prologue
#pragma unroll
    for (int j = 0; j < 4; j++) { GLDS16(asrc[j], adst[j]); GLDS16(bsrc[j], bdst[j]); }

    int cur = 0;
    for (int it = 0; it < DFF / 64; ++it) {         // 32 K-steps
        if (it + 1 < DFF / 64) {
            int kn = (it + 1) * 64;
            int off = (cur ^ 1) * 128 * 64;
#pragma unroll
            for (int j = 0; j < 4; j++) {
                GLDS16(asrc[j] + kn, adst[j] + off);
                GLDS16(bsrc[j] + kn, bdst[j] + off);
            }
            asm volatile("s_waitcnt vmcnt(8)" ::: "memory");
        } else {
            asm volatile("s_waitcnt vmcnt(0)" ::: "memory");
        }
        __builtin_amdgcn_s_barrier();
        __builtin_amdgcn_sched_barrier(0);
        __builtin_amdgcn_s_setprio(1);
        const unsigned short* Ab = &As[cur][0];
        const unsigned short* Bb = &Bs[cur][0];
#pragma unroll
        for (int h = 0; h < 2; h++) {
            bf16x8 af[4], bfv[4];
#pragma unroll
            for (int m = 0; m < 4; m++) {
                int R = wr * 64 + m * 16 + lr;
                af[m] = *(const bf16x8*)&Ab[R * 64 + (((h << 2) + q) ^ (R & 7)) * 8];
            }
#pragma unroll
            for (int n = 0; n < 4; n++) {
                int R = wc * 64 + n * 16 + lr;
                bfv[n] = *(const bf16x8*)&Bb[R * 64 + (((h << 2) + q) ^ (R & 7)) * 8];
            }
#pragma unroll
            for (int m = 0; m < 4; m++)
#pragma unroll
                for (int n = 0; n < 4; n++)
                    acc[m][n] = __builtin_amdgcn_mfma_f32_16x16x32_bf16(bfv[n], af[m], acc[m][n], 0, 0, 0);
        }
        __builtin_amdgcn_s_setprio(0);
        __builtin_amdgcn_sched_barrier(0);
        asm volatile("" ::: "memory");
        __builtin_amdgcn_s_barrier();
        cur ^= 1;
    }

    // epilogue: acc[m][n][j] = Y[r = wr*64+m*16+lr][d = d0 + wc*64 + n*16 + q*4 + j]
#pragma unroll
    for (int m = 0; m < 4; m++) {
        int r = wr * 64 + m * 16 + lr;
        unsigned short* yrow = Y + (size_t)(r0 + r) * DM + d0;
#pragma unroll
        for (int n = 0; n < 4; n++) {
            int dc = wc * 64 + n * 16 + q * 4;
            *(uint2*)(yrow + dc) = make_uint2(pkbf(acc[m][n][0], acc[m][n][1]),
                                              pkbf(acc[m][n][2], acc[m][n][3]));
        }
    }
}

// ---------------- combine: out[t] = p0*(Y[a0]+b2[e0]) + p1*(Y[a1]+b2[e1]) ----------------
__global__ void __launch_bounds__(256) k_combine(const unsigned short* __restrict__ Y,
                                                 const float* __restrict__ b2,
                                                 const int* __restrict__ tokpos,
                                                 const int2* __restrict__ route_e,
                                                 const float2* __restrict__ route_p,
                                                 float* __restrict__ out) {
    int gt = blockIdx.x * 256 + threadIdx.x;
    int token = gt >> 6;
    int cbase = (gt & 63) * 8;
    int2 e = route_e[token];
    float2 p = route_p[token];
    int a0 = tokpos[token * 2], a1 = tokpos[token * 2 + 1];
    s16x8 y0 = *(const s16x8*)(Y + (size_t)a0 * DM + cbase);
    s16x8 y1 = *(const s16x8*)(Y + (size_t)a1 * DM + cbase);
    const float4* bb0 = (const float4*)(b2 + e.x * DM + cbase);
    const float4* bb1 = (const float4*)(b2 + e.y * DM + cbase);
    float4 b00 = bb0[0], b01 = bb0[1];
    float4 b10 = bb1[0], b11 = bb1[1];
    float r[8];
    r[0] = p.x * (bf2f((unsigned short)y0[0]) + b00.x) + p.y * (bf2f((unsigned short)y1[0]) + b10.x);
    r[1] = p.x * (bf2f((unsigned short)y0[1]) + b00.y) + p.y * (bf2f((unsigned short)y1[1]) + b10.y);
    r[2] = p.x * (bf2f((unsigned short)y0[2]) + b00.z) + p.y * (bf2f((unsigned short)y1[2]) + b10.z);
    r[3] = p.x * (bf2f((unsigned short)y0[3]) + b00.w) + p.y * (bf2f((unsigned short)y1[3]) + b10.w);
    r[4] = p.x * (bf2f((unsigned short)y0[4]) + b01.x) + p.y * (bf2f((unsigned short)y1[4]) + b11.x);
    r[5] = p.x * (bf2f((unsigned short)y0[5]) + b01.y) + p.y * (bf2f((unsigned short)y1[5]) + b11.y);
    r[6] = p.x * (bf2f((unsigned short)y0[6]) + b01.z) + p.y * (bf2f((unsigned short)y1[6]) + b11.z);
    r[7] = p.x * (bf2f((unsigned short)y0[7]) + b01.w) + p.y * (bf2f((unsigned short)y1[7]) + b11.w);
    float* op = out + (size_t)token * DM + cbase;
    *(float4*)op       = make_float4(r[0], r[1], r[2], r[3]);
    *(float4*)(op + 4) = make_float4(r[4], r[5], r[6], r[7]);
}

// ---------------- launch ----------------
extern "C" void kernel_launch(void* const* d_in, const int* in_sizes, int n_in,
                              void* d_out, int out_size, void* d_ws, size_t ws_size,
                              hipStream_t stream) {
    const float* x       = (const float*)d_in[0];
    const int*   task_id = (const int*)d_in[1];
    const float* w1      = (const float*)d_in[2];
    const float* b1      = (const float*)d_in[3];
    const float* w2      = (const float*)d_in[4];
    const float* b2      = (const float*)d_in[5];
    const float* temb    = (const float*)d_in[6];
    const float* gw      = (const float*)d_in[7];
    const float* gb      = (const float*)d_in[8];
    float* out = (float*)d_out;

    char* ws = (char*)d_ws;
    double* bstats   = (double*)(ws + WS_BSTATS);
    double* dmean    = (double*)(ws + WS_DMEAN);
    double* drstd    = (double*)(ws + WS_DRSTD);
    double* dcolsum  = (double*)(ws + WS_DCOLSUM);
    double* dtask    = (double*)(ws + WS_DTASK);
    int*    hist     = (int*)(ws + WS_HIST);
    int*    cursor   = (int*)(ws + WS_CURSOR);
    int*    seg_off  = (int*)(ws + WS_SEGOFF);
    int2*   route_e  = (int2*)(ws + WS_ROUTE_E);
    float2* route_p  = (float2*)(ws + WS_ROUTE_P);
    int*    atok     = (int*)(ws + WS_ATOK);
    float*  aprob    = (float*)(ws + WS_APROB);
    int*    tokpos   = (int*)(ws + WS_TOKPOS);
    double* raw      = (double*)(ws + WS_RAW);
    unsigned short* w1t = (unsigned short*)(ws + WS_W1T);
    unsigned short* w2t = (unsigned short*)(ws + WS_W2T);
    unsigned short* xb  = (unsigned short*)(ws + WS_XB);
    unsigned short* Y   = (unsigned short*)(ws + WS_Y);
    unsigned short* H   = (unsigned short*)(ws + WS_H);

    // 128-row tiles per chunk from remaining ws; balance chunks; even for grid%8
    int TPC = (int)((ws_size - (size_t)WS_H) / (size_t)(128 * DFF * 2));
    if (TPC > MAXTILES) TPC = MAXTILES;
    TPC &= ~1;
    if (TPC < 2) TPC = 2;
    {
        int nch = (MAXTILES + TPC - 1) / TPC;
        int bal = (MAXTILES + nch - 1) / nch;
        bal = (bal + 1) & ~1;
        if (bal <= TPC) TPC = bal;
    }

    hipMemsetAsync(ws, 0, WS_HDR_END, stream);
    hipMemsetAsync(ws + WS_ATOK, 0xFF, (size_t)MAXROWS * sizeof(int), stream);

    k_transpose_bf16<<<dim3(DFF / 32, DM / 32, NE), 256, 0, stream>>>(w1, w1t, DM, DFF);
    k_transpose_bf16<<<dim3(DM / 32, DFF / 32, NE), 256, 0, stream>>>(w2, w2t, DFF, DM);

    // fused gate-raw + x->bf16 + stats (single pass over x)
    k_xgate<<<NTOK / 256, 256, 0, stream>>>(x, gw, xb, bstats, raw);
    k_finalize<<<1, 256, 0, stream>>>(bstats, dmean, drstd, dcolsum, dtask,
                                      gw, gb, temb, task_id, out + OUT_TASK);
    k_topk<<<NTOK / 256, 256, 0, stream>>>(raw, dmean, drstd, dcolsum, dtask,
                                           hist, route_e, route_p, out + OUT_TOPK);
    k_offsets_lb<<<1, 64, 0, stream>>>(hist, seg_off, out + OUT_LB);
    k_scatter<<<NTOK / 256, 256, 0, stream>>>(route_e, route_p, seg_off, cursor,
                                              atok, aprob, tokpos);

    for (int t0 = 0; t0 < MAXTILES; t0 += TPC) {
        k_gemm1<<<TPC * 16, 256, 0, stream>>>(xb, w1t, b1, atok, seg_off, H, t0);
        k_gemm2<<<TPC * 4, 256, 0, stream>>>(H, w2t, seg_off, Y, t0);
    }
    k_combine<<<NTOK / 4, 256, 0, stream>>>(Y, b2, tokpos, route_e, route_p, out);
}

// Round 12
// 556.724 us; speedup vs baseline: 1.6762x; 1.0149x over previous
//
#include <hip/hip_runtime.h>

// ---------------- problem constants ----------------
#define NB      8
#define SEQ     4096
#define DM      512
#define DFF     2048
#define NE      8
#define NTOK    32768            // NB*SEQ
#define NPB     2097152          // SEQ*DM elems per batch
#define MAXROWS 66560            // 520 * 128 >= 65536 + 8*127
#define MAXTILES 520             // 128-row tiles

// output layout (fp32 elements)
#define OUT_LB   16777216
#define OUT_TOPK 16777217
#define OUT_TASK 16842753

// ws byte offsets
#define WS_BSTATS   0            // double[128][2] (per xgate block)
#define WS_DMEAN    2048
#define WS_DRSTD    2112
#define WS_DCOLSUM  2176
#define WS_DTASK    2240         // double[8][8]
#define WS_HIST     2752
#define WS_CURSOR   2784
#define WS_SEGOFF   2816
#define WS_HDR_END  2944
#define WS_ROUTE_E  2944         // int2[32768]
#define WS_ROUTE_P  265088       // float2[32768]
#define WS_ATOK     527232       // int[66560]
#define WS_APROB    793472       // float[66560]
#define WS_TOKPOS   1059712      // int[32768*2]
#define WS_RAW      1321856      // double[32768][8]
#define WS_W1T      3419008      // ushort[8*2048*512]
#define WS_W2T      20196224     // ushort[8*512*2048]
#define WS_XB       36973440     // ushort[32768*512]
#define WS_Y        70527872     // ushort[66560*512]
#define WS_H        138685312    // ushort[TPC*128*2048]

typedef __attribute__((ext_vector_type(4))) float  f32x4;
typedef __attribute__((ext_vector_type(8))) __bf16 bf16x8;
typedef __attribute__((ext_vector_type(8))) short  s16x8;

__device__ __forceinline__ unsigned short f2bf(float f) {
    unsigned int u = __builtin_bit_cast(unsigned int, f);
    u += 0x7FFFu + ((u >> 16) & 1u);
    return (unsigned short)(u >> 16);
}
__device__ __forceinline__ float bf2f(unsigned short b) {
    unsigned int u = ((unsigned int)b) << 16;
    return __builtin_bit_cast(float, u);
}
__device__ __forceinline__ unsigned int pkbf(float a, float b) {
    unsigned int r;
    asm("v_cvt_pk_bf16_f32 %0, %1, %2" : "=v"(r) : "v"(a), "v"(b));
    return r;
}

#define GLDS16(g, l)                                                              \
    __builtin_amdgcn_global_load_lds(                                             \
        (const __attribute__((address_space(1))) unsigned int*)(const void*)(g),  \
        (__attribute__((address_space(3))) unsigned int*)(void*)(l), 16, 0, 0)

// ---------------- weight transpose + bf16 convert ----------------
__global__ void k_transpose_bf16(const float* __restrict__ in,
                                 unsigned short* __restrict__ outT,
                                 int R, int C) {
    __shared__ float tile[32][33];
    int e = blockIdx.z;
    const float* src = in + (size_t)e * R * C;
    unsigned short* dst = outT + (size_t)e * R * C;
    int tx = threadIdx.x & 31, ty = threadIdx.x >> 5;
    int c0 = blockIdx.x * 32, r0 = blockIdx.y * 32;
#pragma unroll
    for (int i = 0; i < 4; i++) {
        int r = r0 + ty + i * 8;
        tile[ty + i * 8][tx] = src[(size_t)r * C + c0 + tx];
    }
    __syncthreads();
#pragma unroll
    for (int i = 0; i < 4; i++) {
        int rr = c0 + ty + i * 8;
        dst[(size_t)rr * R + r0 + tx] = f2bf(tile[tx][ty + i * 8]);
    }
}

// ---------------- fused: gate raw logits (fp64) + x->bf16 + batch stats ----------------
__global__ void __launch_bounds__(256) k_xgate(const float* __restrict__ x,
                                               const float* __restrict__ gw,
                                               unsigned short* __restrict__ xb,
                                               double* __restrict__ bstats,
                                               double* __restrict__ raw) {
    __shared__ float gws[DM * 8];    // 16 KB
    int t = threadIdx.x;
#pragma unroll
    for (int i = 0; i < 16; i++) gws[i * 256 + t] = gw[i * 256 + t];
    __syncthreads();

    int token = blockIdx.x * 256 + t;
    const float4* xp = (const float4*)(x + (size_t)token * DM);
    unsigned short* xbp = xb + (size_t)token * DM;

    double acc[8] = {0, 0, 0, 0, 0, 0, 0, 0};
    double s = 0.0, ss = 0.0;
#pragma unroll 2
    for (int i = 0; i < 128; i += 2) {
        float4 v0 = xp[i];
        float4 v1 = xp[i + 1];
        {
            double dx = v0.x, dy = v0.y, dz = v0.z, dw = v0.w;
            const float* g = &gws[i * 32];
#pragma unroll
            for (int e = 0; e < 8; e++)
                acc[e] += dx * (double)g[e] + dy * (double)g[8 + e]
                        + dz * (double)g[16 + e] + dw * (double)g[24 + e];
            s  += dx + dy + dz + dw;
            ss += dx * dx + dy * dy + dz * dz + dw * dw;
        }
        {
            double dx = v1.x, dy = v1.y, dz = v1.z, dw = v1.w;
            const float* g = &gws[(i + 1) * 32];
#pragma unroll
            for (int e = 0; e < 8; e++)
                acc[e] += dx * (double)g[e] + dy * (double)g[8 + e]
                        + dz * (double)g[16 + e] + dw * (double)g[24 + e];
            s  += dx + dy + dz + dw;
            ss += dx * dx + dy * dy + dz * dz + dw * dw;
        }
        s16x8 o = {(short)f2bf(v0.x), (short)f2bf(v0.y), (short)f2bf(v0.z), (short)f2bf(v0.w),
                   (short)f2bf(v1.x), (short)f2bf(v1.y), (short)f2bf(v1.z), (short)f2bf(v1.w)};
        *(s16x8*)(xbp + i * 4) = o;
    }
#pragma unroll
    for (int e = 0; e < 8; e++) raw[(size_t)token * 8 + e] = acc[e];

    for (int o = 32; o; o >>= 1) { s += __shfl_down(s, o); ss += __shfl_down(ss, o); }
    __shared__ double as_[4], ass_[4];
    int w = t >> 6;
    if ((t & 63) == 0) { as_[w] = s; ass_[w] = ss; }
    __syncthreads();
    if (t == 0) {
        s  = as_[0] + as_[1] + as_[2] + as_[3];
        ss = ass_[0] + ass_[1] + ass_[2] + ass_[3];
        bstats[blockIdx.x * 2]     = s;
        bstats[blockIdx.x * 2 + 1] = ss;
    }
}

// ---------------- finalize mean/rstd, gate colsum, task terms ----------------
__global__ void k_finalize(const double* __restrict__ bstats,
                           double* __restrict__ dmean, double* __restrict__ drstd,
                           double* __restrict__ dcolsum, double* __restrict__ dtask,
                           const float* __restrict__ gw, const float* __restrict__ gb,
                           const float* __restrict__ temb, const int* __restrict__ task_id,
                           float* __restrict__ out_task) {
    int t = threadIdx.x;
    if (t < 8) {
        double s = 0.0, ss = 0.0;
        for (int i = 0; i < 16; i++) {          // 16 xgate blocks per batch
            s  += bstats[(t * 16 + i) * 2];
            ss += bstats[(t * 16 + i) * 2 + 1];
        }
        double N = (double)NPB;
        double m = s / N;
        double var = ss / N - m * m;
        dmean[t] = m;
        drstd[t] = 1.0 / sqrt(var + 1e-5);
    }
    __shared__ double colp[32][8];
    {
        int e = t & 7, g = t >> 3;
        double a = 0.0;
        for (int r = g * 16; r < g * 16 + 16; r++) a += (double)gw[r * 8 + e];
        colp[g][e] = a;
    }
    __syncthreads();
    if (t < 8) {
        double a = 0.0;
        for (int g = 0; g < 32; g++) a += colp[g][t];
        dcolsum[t] = a;
    }
    if (t < 64) {
        int b2 = t >> 3, e = t & 7;
        int tid = task_id[b2];
        double a = (double)gb[e];
        for (int d = 0; d < 64; d++)
            a += (double)temb[tid * 64 + d] * (double)gw[(512 + d) * 8 + e];
        dtask[t] = a;
    }
    if (t < 8) out_task[t] = (float)task_id[t];
}

// ---------------- top-2 from raw logits ----------------
__global__ void __launch_bounds__(256) k_topk(const double* __restrict__ raw,
                                              const double* __restrict__ dmean,
                                              const double* __restrict__ drstd,
                                              const double* __restrict__ dcolsum,
                                              const double* __restrict__ dtask,
                                              int* __restrict__ hist,
                                              int2* __restrict__ route_e,
                                              float2* __restrict__ route_p,
                                              float* __restrict__ out_topk) {
    __shared__ int lh[8];
    int t = threadIdx.x;
    if (t < 8) lh[t] = 0;
    __syncthreads();
    int token = blockIdx.x * 256 + t;
    int b = token >> 12;
    double m = dmean[b], rs = drstd[b];
    double lg[8];
#pragma unroll
    for (int e = 0; e < 8; e++)
        lg[e] = rs * (raw[(size_t)token * 8 + e] - m * dcolsum[e]) + dtask[b * 8 + e];
    int i0 = 0;
#pragma unroll
    for (int e = 1; e < 8; e++) if (lg[e] > lg[i0]) i0 = e;
    int i1 = (i0 == 0) ? 1 : 0;
#pragma unroll
    for (int e = 0; e < 8; e++) if (e != i0 && lg[e] > lg[i1]) i1 = e;
    double d = exp(lg[i1] - lg[i0]);
    double p0 = 1.0 / (1.0 + d);
    double p1 = d / (1.0 + d);
    out_topk[token * 2]     = (float)i0;
    out_topk[token * 2 + 1] = (float)i1;
    atomicAdd(&lh[i0], 1);
    atomicAdd(&lh[i1], 1);
    route_e[token] = make_int2(i0, i1);
    route_p[token] = make_float2((float)p0, (float)p1);
    __syncthreads();
    if (t < 8) atomicAdd(&hist[t], lh[t]);
}

// ---------------- segment offsets (128-padded) + lb_loss ----------------
__global__ void k_offsets_lb(const int* __restrict__ hist, int* __restrict__ seg_off,
                             float* __restrict__ out_lb) {
    if (threadIdx.x == 0) {
        int off = 0;
        double ssd = 0.0;
        for (int e = 0; e < 8; e++) {
            seg_off[e] = off;
            off += (hist[e] + 127) & ~127;
            double d = (double)hist[e] - 8192.0;
            ssd += d * d;
        }
        seg_off[8] = off;
        double stdv = sqrt(ssd / 7.0);
        double m = 8192.0 + 1e-6;
        double r = stdv / m;
        *out_lb = (float)(r * r);
    }
}

// ---------------- scatter: LDS-aggregated two-level + inverse map ----------------
__global__ void __launch_bounds__(256) k_scatter(const int2* __restrict__ route_e,
                                                 const float2* __restrict__ route_p,
                                                 const int* __restrict__ seg_off,
                                                 int* __restrict__ cursor,
                                                 int* __restrict__ atok,
                                                 float* __restrict__ aprob,
                                                 int* __restrict__ tokpos) {
    __shared__ int lcount[8];
    __shared__ int lbase[8];
    int t = threadIdx.x;
    if (t < 8) lcount[t] = 0;
    __syncthreads();
    int tok = blockIdx.x * 256 + t;
    int2 e = route_e[tok];
    float2 p = route_p[tok];
    int p0 = atomicAdd(&lcount[e.x], 1);
    int p1 = atomicAdd(&lcount[e.y], 1);
    __syncthreads();
    if (t < 8) lbase[t] = atomicAdd(&cursor[t], lcount[t]);
    __syncthreads();
    int a0 = seg_off[e.x] + lbase[e.x] + p0;
    atok[a0] = tok; aprob[a0] = p.x;
    int a1 = seg_off[e.y] + lbase[e.y] + p1;
    atok[a1] = tok; aprob[a1] = p.y;
    tokpos[tok * 2]     = a0;
    tokpos[tok * 2 + 1] = a1;
}

// ============ MFMA GEMMs: r7-proven 2-phase double-buffered pipeline ============
// LDS: As[2]/Bs[2], XOR-swizzled [128][64] tiles staged via global_load_lds(16B).
// Per iter: issue next-tile stage -> s_waitcnt vmcnt(8) (counted; prefetch stays
// in flight) -> s_barrier -> ds_read+MFMA (setprio 1) -> s_barrier -> flip.
// mfma(bfv, af): lane's 4 acc elems = 4 consecutive OUTPUT COLUMNS.

// ---------------- GEMM1: H[chunk] = silu(X_gather @ w1[e] + b1[e]), full DFF ----------------
__global__ void __launch_bounds__(256) k_gemm1(const unsigned short* __restrict__ xb,
                                               const unsigned short* __restrict__ w1t,
                                               const float* __restrict__ b1,
                                               const int* __restrict__ atok,
                                               const int* __restrict__ seg_off,
                                               unsigned short* __restrict__ H,
                                               int t0) {
    int nwg = (int)gridDim.x;                       // TPC*16, multiple of 8
    int bid = (int)blockIdx.x;
    int wg = (bid & 7) * (nwg >> 3) + (bid >> 3);   // XCD-chunked logical id
    int xt = wg >> 4, y = wg & 15;                  // NY = 16
    int r0 = (t0 + xt) * 128;
    if (r0 >= seg_off[8]) return;
    int e = 0;
    while (seg_off[e + 1] <= r0) e++;
    int f0 = y * 128;

    int tid = threadIdx.x;
    int w = tid >> 6, l = tid & 63;
    int c = l & 7;

    __shared__ __align__(16) unsigned short As[2][128 * 64];
    __shared__ __align__(16) unsigned short Bs[2][128 * 64];

    const unsigned short* asrc[4];
    const unsigned short* bsrc[4];
    unsigned short*       adst[4];
    unsigned short*       bdst[4];
#pragma unroll
    for (int j = 0; j < 4; j++) {
        int R = w * 32 + j * 8 + (l >> 3);
        int cs = c ^ (R & 7);
        int tok = atok[r0 + R]; if (tok < 0) tok = 0;
        asrc[j] = xb + (size_t)tok * DM + cs * 8;
        bsrc[j] = w1t + ((size_t)e * DFF + f0 + R) * DM + cs * 8;
        adst[j] = &As[0][(size_t)(w * 32 + j * 8) * 64];
        bdst[j] = &Bs[0][(size_t)(w * 32 + j * 8) * 64];
    }

    f32x4 acc[4][4] = {};
    int wr = w >> 1, wc = w & 1, lr = l & 15, q = l >> 4;

    // prologue: stage k-step 0 into buffer 0
#pragma unroll
    for (int j = 0; j < 4; j++) { GLDS16(asrc[j], adst[j]); GLDS16(bsrc[j], bdst[j]); }

    int cur = 0;
    for (int it = 0; it < DM / 64; ++it) {          // 8 K-steps
        if (it + 1 < DM / 64) {
            int kn = (it + 1) * 64;
            int off = (cur ^ 1) * 128 * 64;
#pragma unroll
            for (int j = 0; j < 4; j++) {
                GLDS16(asrc[j] + kn, adst[j] + off);
                GLDS16(bsrc[j] + kn, bdst[j] + off);
            }
            asm volatile("s_waitcnt vmcnt(8)" ::: "memory");
        } else {
            asm volatile("s_waitcnt vmcnt(0)" ::: "memory");
        }
        __builtin_amdgcn_s_barrier();
        __builtin_amdgcn_sched_barrier(0);
        __builtin_amdgcn_s_setprio(1);
        const unsigned short* Ab = &As[cur][0];
        const unsigned short* Bb = &Bs[cur][0];
#pragma unroll
        for (int h = 0; h < 2; h++) {
            bf16x8 af[4], bfv[4];
#pragma unroll
            for (int m = 0; m < 4; m++) {
                int R = wr * 64 + m * 16 + lr;
                af[m] = *(const bf16x8*)&Ab[R * 64 + (((h << 2) + q) ^ (R & 7)) * 8];
            }
#pragma unroll
            for (int n = 0; n < 4; n++) {
                int R = wc * 64 + n * 16 + lr;
                bfv[n] = *(const bf16x8*)&Bb[R * 64 + (((h << 2) + q) ^ (R & 7)) * 8];
            }
#pragma unroll
            for (int m = 0; m < 4; m++)
#pragma unroll
                for (int n = 0; n < 4; n++)
                    acc[m][n] = __builtin_amdgcn_mfma_f32_16x16x32_bf16(bfv[n], af[m], acc[m][n], 0, 0, 0);
        }
        __builtin_amdgcn_s_setprio(0);
        __builtin_amdgcn_sched_barrier(0);
        asm volatile("" ::: "memory");
        __builtin_amdgcn_s_barrier();
        cur ^= 1;
    }

    // epilogue: acc[m][n][j] = H[r = wr*64+m*16+lr][f = f0 + wc*64 + n*16 + q*4 + j]
    const float* b1e = b1 + e * DFF + f0;
#pragma unroll
    for (int m = 0; m < 4; m++) {
        int r = wr * 64 + m * 16 + lr;
        unsigned short* hrow = H + ((size_t)xt * 128 + r) * DFF + f0;
#pragma unroll
        for (int n = 0; n < 4; n++) {
            int fc = wc * 64 + n * 16 + q * 4;
            float4 bias = *(const float4*)(b1e + fc);
            float v0 = acc[m][n][0] + bias.x; v0 = v0 / (1.0f + __expf(-v0));
            float v1 = acc[m][n][1] + bias.y; v1 = v1 / (1.0f + __expf(-v1));
            float v2 = acc[m][n][2] + bias.z; v2 = v2 / (1.0f + __expf(-v2));
            float v3 = acc[m][n][3] + bias.w; v3 = v3 / (1.0f + __expf(-v3));
            *(uint2*)(hrow + fc) = make_uint2(pkbf(v0, v1), pkbf(v2, v3));
        }
    }
}

// ---------------- GEMM2: Y[aidx] = H[chunk] @ w2[e]  (K=2048, plain bf16 stores) ----------------
__global__ void __launch_bounds__(256) k_gemm2(const unsigned short* __restrict__ H,
                                               const unsigned short* __restrict__ w2t,
                                               const int* __restrict__ seg_off,
                                               unsigned short* __restrict__ Y,
                                               int t0) {
    int nwg = (int)gridDim.x;                       // TPC*4, TPC even -> %8==0
    int bid = (int)blockIdx.x;
    int wg = (bid & 7) * (nwg >> 3) + (bid >> 3);
    int xt = wg >> 2, y = wg & 3;                   // NY = 4
    int r0 = (t0 + xt) * 128;
    if (r0 >= seg_off[8]) return;
    int e = 0;
    while (seg_off[e + 1] <= r0) e++;
    int d0 = y * 128;

    int tid = threadIdx.x;
    int w = tid >> 6, l = tid & 63;
    int c = l & 7;

    __shared__ __align__(16) unsigned short As[2][128 * 64];
    __shared__ __align__(16) unsigned short Bs[2][128 * 64];

    const unsigned short* asrc[4];
    const unsigned short* bsrc[4];
    unsigned short*       adst[4];
    unsigned short*       bdst[4];
#pragma unroll
    for (int j = 0; j < 4; j++) {
        int R = w * 32 + j * 8 + (l >> 3);
        int cs = c ^ (R & 7);
        asrc[j] = H + ((size_t)xt * 128 + R) * DFF + cs * 8;
        bsrc[j] = w2t + ((size_t)e * DM + d0 + R) * DFF + cs * 8;
        adst[j] = &As[0][(size_t)(w * 32 + j * 8) * 64];
        bdst[j] = &Bs[0][(size_t)(w * 32 + j * 8) * 64];
    }

    f32x4 acc[4][4] = {};
    int wr = w >> 1, wc = w & 1, lr = l & 15, q = l >> 4;

    // prologue
#pragma unroll
    for (int j = 0; j < 4; j++) { GLDS16(asrc[j], adst[j]); GLDS16(bsrc[j], bdst[j]); }

    int cur = 0;
    for (int it = 0; it < DFF / 64; ++it) {         // 32 K-steps
        if (it + 1 < DFF / 64) {
            int kn = (it + 1) * 64;
            int off = (cur ^ 1) * 128 * 64;
#pragma unroll
            for (int j = 0; j < 4; j++) {
                GLDS16(asrc[j] + kn, adst[j] + off);
                GLDS16(bsrc[j] + kn, bdst[j] + off);
            }
            asm volatile("s_waitcnt vmcnt(8)" ::: "memory");
        } else {
            asm volatile("s_waitcnt vmcnt(0)" ::: "memory");
        }
        __builtin_amdgcn_s_barrier();
        __builtin_amdgcn_sched_barrier(0);
        __builtin_amdgcn_s_setprio(1);
        const unsigned short* Ab = &As[cur][0];
        const unsigned short* Bb = &Bs[cur][0];
#pragma unroll
        for (int h = 0; h < 2; h++) {
            bf16x8 af[4], bfv[4];
#pragma unroll
            for (int m = 0; m < 4; m++) {
                int R = wr * 64 + m * 16 + lr;
                af[m] = *(const bf16x8*)&Ab[R * 64 + (((h << 2) + q) ^ (R & 7)) * 8];
            }
#pragma unroll
            for (int n = 0; n < 4; n++) {
                int R = wc * 64 + n * 16 + lr;
                bfv[n] = *(const bf16x8*)&Bb[R * 64 + (((h << 2) + q) ^ (R & 7)) * 8];
            }
#pragma unroll
            for (int m = 0; m < 4; m++)
#pragma unroll
                for (int n = 0; n < 4; n++)
                    acc[m][n] = __builtin_amdgcn_mfma_f32_16x16x32_bf16(bfv[n], af[m], acc[m][n], 0, 0, 0);
        }
        __builtin_amdgcn_s_setprio(0);
        __builtin_amdgcn_sched_barrier(0);
        asm volatile("" ::: "memory");
        __builtin_amdgcn_s_barrier();
        cur ^= 1;
    }

    // epilogue: acc[m][n][j] = Y[r = wr*64+m*16+lr][d = d0 + wc*64 + n*16 + q*4 + j]
#pragma unroll
    for (int m = 0; m < 4; m++) {
        int r = wr * 64 + m * 16 + lr;
        unsigned short* yrow = Y + (size_t)(r0 + r) * DM + d0;
#pragma unroll
        for (int n = 0; n < 4; n++) {
            int dc = wc * 64 + n * 16 + q * 4;
            *(uint2*)(yrow + dc) = make_uint2(pkbf(acc[m][n][0], acc[m][n][1]),
                                              pkbf(acc[m][n][2], acc[m][n][3]));
        }
    }
}

// ---------------- combine: out[t] = p0*(Y[a0]+b2[e0]) + p1*(Y[a1]+b2[e1]) ----------------
__global__ void __launch_bounds__(256) k_combine(const unsigned short* __restrict__ Y,
                                                 const float* __restrict__ b2,
                                                 const int* __restrict__ tokpos,
                                                 const int2* __restrict__ route_e,
                                                 const float2* __restrict__ route_p,
                                                 float* __restrict__ out) {
    int gt = blockIdx.x * 256 + threadIdx.x;
    int token = gt >> 6;
    int cbase = (gt & 63) * 8;
    int2 e = route_e[token];
    float2 p = route_p[token];
    int a0 = tokpos[token * 2], a1 = tokpos[token * 2 + 1];
    s16x8 y0 = *(const s16x8*)(Y + (size_t)a0 * DM + cbase);
    s16x8 y1 = *(const s16x8*)(Y + (size_t)a1 * DM + cbase);
    const float4* bb0 = (const float4*)(b2 + e.x * DM + cbase);
    const float4* bb1 = (const float4*)(b2 + e.y * DM + cbase);
    float4 b00 = bb0[0], b01 = bb0[1];
    float4 b10 = bb1[0], b11 = bb1[1];
    float r[8];
    r[0] = p.x * (bf2f((unsigned short)y0[0]) + b00.x) + p.y * (bf2f((unsigned short)y1[0]) + b10.x);
    r[1] = p.x * (bf2f((unsigned short)y0[1]) + b00.y) + p.y * (bf2f((unsigned short)y1[1]) + b10.y);
    r[2] = p.x * (bf2f((unsigned short)y0[2]) + b00.z) + p.y * (bf2f((unsigned short)y1[2]) + b10.z);
    r[3] = p.x * (bf2f((unsigned short)y0[3]) + b00.w) + p.y * (bf2f((unsigned short)y1[3]) + b10.w);
    r[4] = p.x * (bf2f((unsigned short)y0[4]) + b01.x) + p.y * (bf2f((unsigned short)y1[4]) + b11.x);
    r[5] = p.x * (bf2f((unsigned short)y0[5]) + b01.y) + p.y * (bf2f((unsigned short)y1[5]) + b11.y);
    r[6] = p.x * (bf2f((unsigned short)y0[6]) + b01.z) + p.y * (bf2f((unsigned short)y1[6]) + b11.z);
    r[7] = p.x * (bf2f((unsigned short)y0[7]) + b01.w) + p.y * (bf2f((unsigned short)y1[7]) + b11.w);
    float* op = out + (size_t)token * DM + cbase;
    *(float4*)op       = make_float4(r[0], r[1], r[2], r[3]);
    *(float4*)(op + 4) = make_float4(r[4], r[5], r[6], r[7]);
}

// ---------------- launch ----------------
extern "C" void kernel_launch(void* const* d_in, const int* in_sizes, int n_in,
                              void* d_out, int out_size, void* d_ws, size_t ws_size,
                              hipStream_t stream) {
    const float* x       = (const float*)d_in[0];
    const int*   task_id = (const int*)d_in[1];
    const float* w1      = (const float*)d_in[2];
    const float* b1      = (const float*)d_in[3];
    const float* w2      = (const float*)d_in[4];
    const float* b2      = (const float*)d_in[5];
    const float* temb    = (const float*)d_in[6];
    const float* gw      = (const float*)d_in[7];
    const float* gb      = (const float*)d_in[8];
    float* out = (float*)d_out;

    char* ws = (char*)d_ws;
    double* bstats   = (double*)(ws + WS_BSTATS);
    double* dmean    = (double*)(ws + WS_DMEAN);
    double* drstd    = (double*)(ws + WS_DRSTD);
    double* dcolsum  = (double*)(ws + WS_DCOLSUM);
    double* dtask    = (double*)(ws + WS_DTASK);
    int*    hist     = (int*)(ws + WS_HIST);
    int*    cursor   = (int*)(ws + WS_CURSOR);
    int*    seg_off  = (int*)(ws + WS_SEGOFF);
    int2*   route_e  = (int2*)(ws + WS_ROUTE_E);
    float2* route_p  = (float2*)(ws + WS_ROUTE_P);
    int*    atok     = (int*)(ws + WS_ATOK);
    float*  aprob    = (float*)(ws + WS_APROB);
    int*    tokpos   = (int*)(ws + WS_TOKPOS);
    double* raw      = (double*)(ws + WS_RAW);
    unsigned short* w1t = (unsigned short*)(ws + WS_W1T);
    unsigned short* w2t = (unsigned short*)(ws + WS_W2T);
    unsigned short* xb  = (unsigned short*)(ws + WS_XB);
    unsigned short* Y   = (unsigned short*)(ws + WS_Y);
    unsigned short* H   = (unsigned short*)(ws + WS_H);

    // 128-row tiles per chunk. Cap at 128 so grids quantize exactly to the
    // 512-block concurrency limit (2 blocks/CU x 256 CU at 64 KB LDS):
    // gemm1 grid = 16*TPC = 2048 (4 exact rounds), gemm2 grid = 4*TPC = 512 (1 round).
    int TPC = (int)((ws_size - (size_t)WS_H) / (size_t)(128 * DFF * 2));
    if (TPC > 128) TPC = 128;
    TPC &= ~1;
    if (TPC < 2) TPC = 2;

    hipMemsetAsync(ws, 0, WS_HDR_END, stream);
    hipMemsetAsync(ws + WS_ATOK, 0xFF, (size_t)MAXROWS * sizeof(int), stream);

    k_transpose_bf16<<<dim3(DFF / 32, DM / 32, NE), 256, 0, stream>>>(w1, w1t, DM, DFF);
    k_transpose_bf16<<<dim3(DM / 32, DFF / 32, NE), 256, 0, stream>>>(w2, w2t, DFF, DM);

    // fused gate-raw + x->bf16 + stats (single pass over x)
    k_xgate<<<NTOK / 256, 256, 0, stream>>>(x, gw, xb, bstats, raw);
    k_finalize<<<1, 256, 0, stream>>>(bstats, dmean, drstd, dcolsum, dtask,
                                      gw, gb, temb, task_id, out + OUT_TASK);
    k_topk<<<NTOK / 256, 256, 0, stream>>>(raw, dmean, drstd, dcolsum, dtask,
                                           hist, route_e, route_p, out + OUT_TOPK);
    k_offsets_lb<<<1, 64, 0, stream>>>(hist, seg_off, out + OUT_LB);
    k_scatter<<<NTOK / 256, 256, 0, stream>>>(route_e, route_p, seg_off, cursor,
                                              atok, aprob, tokpos);

    for (int t0 = 0; t0 < MAXTILES; t0 += TPC) {
        k_gemm1<<<TPC * 16, 256, 0, stream>>>(xb, w1t, b1, atok, seg_off, H, t0);
        k_gemm2<<<TPC * 4, 256, 0, stream>>>(H, w2t, seg_off, Y, t0);
    }
    k_combine<<<NTOK / 4, 256, 0, stream>>>(Y, b2, tokpos, route_e, route_p, out);
}

// Round 13
// 545.816 us; speedup vs baseline: 1.7097x; 1.0200x over previous
//
#include <hip/hip_runtime.h>

// ---------------- problem constants ----------------
#define NB      8
#define SEQ     4096
#define DM      512
#define DFF     2048
#define NE      8
#define NTOK    32768            // NB*SEQ
#define NPB     2097152          // SEQ*DM elems per batch
#define MAXROWS 66560            // 520 * 128 >= 65536 + 8*127
#define MAXTILES 520             // 128-row tiles

// output layout (fp32 elements)
#define OUT_LB   16777216
#define OUT_TOPK 16777217
#define OUT_TASK 16842753

// ws byte offsets
#define WS_BSTATS   0            // double[512][2] (per xgate block)
#define WS_DMEAN    8192
#define WS_DRSTD    8256
#define WS_DCOLSUM  8320
#define WS_DTASK    8384         // double[8][8]
#define WS_HIST     8896
#define WS_CURSOR   8928
#define WS_SEGOFF   8960
#define WS_HDR_END  9216
#define WS_ROUTE_E  9216         // int2[32768]
#define WS_ROUTE_P  271360       // float2[32768]
#define WS_ATOK     533504       // int[66560]
#define WS_APROB    799744       // float[66560]
#define WS_TOKPOS   1065984      // int[32768*2]
#define WS_RAW      1328128      // double[32768][8]
#define WS_W1T      3425280      // ushort[8*2048*512]
#define WS_W2T      20202496     // ushort[8*512*2048]
#define WS_XB       36979712     // ushort[32768*512]
#define WS_Y        70534144     // ushort[66560*512]
#define WS_H        138691584    // ushort[TPC*128*2048]

typedef __attribute__((ext_vector_type(4))) float  f32x4;
typedef __attribute__((ext_vector_type(8))) __bf16 bf16x8;
typedef __attribute__((ext_vector_type(8))) short  s16x8;

__device__ __forceinline__ unsigned short f2bf(float f) {
    unsigned int u = __builtin_bit_cast(unsigned int, f);
    u += 0x7FFFu + ((u >> 16) & 1u);
    return (unsigned short)(u >> 16);
}
__device__ __forceinline__ float bf2f(unsigned short b) {
    unsigned int u = ((unsigned int)b) << 16;
    return __builtin_bit_cast(float, u);
}
__device__ __forceinline__ unsigned int pkbf(float a, float b) {
    unsigned int r;
    asm("v_cvt_pk_bf16_f32 %0, %1, %2" : "=v"(r) : "v"(a), "v"(b));
    return r;
}

#define GLDS16(g, l)                                                              \
    __builtin_amdgcn_global_load_lds(                                             \
        (const __attribute__((address_space(1))) unsigned int*)(const void*)(g),  \
        (__attribute__((address_space(3))) unsigned int*)(void*)(l), 16, 0, 0)

// ---------------- weight transpose + bf16 convert ----------------
__global__ void k_transpose_bf16(const float* __restrict__ in,
                                 unsigned short* __restrict__ outT,
                                 int R, int C) {
    __shared__ float tile[32][33];
    int e = blockIdx.z;
    const float* src = in + (size_t)e * R * C;
    unsigned short* dst = outT + (size_t)e * R * C;
    int tx = threadIdx.x & 31, ty = threadIdx.x >> 5;
    int c0 = blockIdx.x * 32, r0 = blockIdx.y * 32;
#pragma unroll
    for (int i = 0; i < 4; i++) {
        int r = r0 + ty + i * 8;
        tile[ty + i * 8][tx] = src[(size_t)r * C + c0 + tx];
    }
    __syncthreads();
#pragma unroll
    for (int i = 0; i < 4; i++) {
        int rr = c0 + ty + i * 8;
        dst[(size_t)rr * R + r0 + tx] = f2bf(tile[tx][ty + i * 8]);
    }
}

// ---------------- fused: gate raw logits (fp64) + x->bf16 + batch stats ----------------
// 4 THREADS per token (128 dims each) -> 131072 threads (2 waves/SIMD; the r12
// version had 0.5 waves/SIMD and was latency-bound at 63 us). Quarter regions of
// gate_w in LDS are padded (+8 floats) so the 4 concurrent quarter-addresses hit
// banks {0,8,16,24}: conflict-free. acc[8] reduced across the 4 lanes via shfl_xor.
#define GQPAD 1032               // 128 rows * 8 + 8 pad floats
__global__ void __launch_bounds__(256) k_xgate(const float* __restrict__ x,
                                               const float* __restrict__ gw,
                                               unsigned short* __restrict__ xb,
                                               double* __restrict__ bstats,
                                               double* __restrict__ raw) {
    __shared__ float gws[4 * GQPAD];   // ~16.5 KB
    int t = threadIdx.x;
#pragma unroll
    for (int i = 0; i < 16; i++) {
        int idx = i * 256 + t;               // 0..4095 over gw rows 0..511
        int row = idx >> 3, e = idx & 7;
        gws[(row >> 7) * GQPAD + (row & 127) * 8 + e] = gw[idx];
    }
    __syncthreads();

    int token = blockIdx.x * 64 + (t >> 2);
    int q = t & 3;                            // dim quarter
    const float4* xp = (const float4*)(x + (size_t)token * DM + q * 128);
    unsigned short* xbp = xb + (size_t)token * DM + q * 128;
    const float* gq = &gws[q * GQPAD];

    double acc[8] = {0, 0, 0, 0, 0, 0, 0, 0};
    double s = 0.0, ss = 0.0;
#pragma unroll 4
    for (int i = 0; i < 32; i += 2) {
        float4 v0 = xp[i];
        float4 v1 = xp[i + 1];
        {
            double dx = v0.x, dy = v0.y, dz = v0.z, dw = v0.w;
            const float* g = &gq[i * 32];
#pragma unroll
            for (int e = 0; e < 8; e++)
                acc[e] += dx * (double)g[e] + dy * (double)g[8 + e]
                        + dz * (double)g[16 + e] + dw * (double)g[24 + e];
            s  += dx + dy + dz + dw;
            ss += dx * dx + dy * dy + dz * dz + dw * dw;
        }
        {
            double dx = v1.x, dy = v1.y, dz = v1.z, dw = v1.w;
            const float* g = &gq[(i + 1) * 32];
#pragma unroll
            for (int e = 0; e < 8; e++)
                acc[e] += dx * (double)g[e] + dy * (double)g[8 + e]
                        + dz * (double)g[16 + e] + dw * (double)g[24 + e];
            s  += dx + dy + dz + dw;
            ss += dx * dx + dy * dy + dz * dz + dw * dw;
        }
        s16x8 o = {(short)f2bf(v0.x), (short)f2bf(v0.y), (short)f2bf(v0.z), (short)f2bf(v0.w),
                   (short)f2bf(v1.x), (short)f2bf(v1.y), (short)f2bf(v1.z), (short)f2bf(v1.w)};
        *(s16x8*)(xbp + i * 4) = o;
    }

    // combine the 4 dim-quarters (lanes q=0..3 within each 4-lane group)
#pragma unroll
    for (int e = 0; e < 8; e++) {
        acc[e] += __shfl_xor(acc[e], 1);
        acc[e] += __shfl_xor(acc[e], 2);
    }
    if (q == 0) {
#pragma unroll
        for (int e = 0; e < 8; e++) raw[(size_t)token * 8 + e] = acc[e];
    }

    // block stats reduction (fp64)
    for (int o = 32; o; o >>= 1) { s += __shfl_down(s, o); ss += __shfl_down(ss, o); }
    __shared__ double as_[4], ass_[4];
    int w = t >> 6;
    if ((t & 63) == 0) { as_[w] = s; ass_[w] = ss; }
    __syncthreads();
    if (t == 0) {
        s  = as_[0] + as_[1] + as_[2] + as_[3];
        ss = ass_[0] + ass_[1] + ass_[2] + ass_[3];
        bstats[blockIdx.x * 2]     = s;
        bstats[blockIdx.x * 2 + 1] = ss;
    }
}

// ---------------- finalize mean/rstd, gate colsum, task terms ----------------
__global__ void k_finalize(const double* __restrict__ bstats,
                           double* __restrict__ dmean, double* __restrict__ drstd,
                           double* __restrict__ dcolsum, double* __restrict__ dtask,
                           const float* __restrict__ gw, const float* __restrict__ gb,
                           const float* __restrict__ temb, const int* __restrict__ task_id,
                           float* __restrict__ out_task) {
    int t = threadIdx.x;
    if (t < 8) {
        double s = 0.0, ss = 0.0;
        for (int i = 0; i < 64; i++) {          // 64 xgate blocks per batch
            s  += bstats[(t * 64 + i) * 2];
            ss += bstats[(t * 64 + i) * 2 + 1];
        }
        double N = (double)NPB;
        double m = s / N;
        double var = ss / N - m * m;
        dmean[t] = m;
        drstd[t] = 1.0 / sqrt(var + 1e-5);
    }
    __shared__ double colp[32][8];
    {
        int e = t & 7, g = t >> 3;
        double a = 0.0;
        for (int r = g * 16; r < g * 16 + 16; r++) a += (double)gw[r * 8 + e];
        colp[g][e] = a;
    }
    __syncthreads();
    if (t < 8) {
        double a = 0.0;
        for (int g = 0; g < 32; g++) a += colp[g][t];
        dcolsum[t] = a;
    }
    if (t < 64) {
        int b2 = t >> 3, e = t & 7;
        int tid = task_id[b2];
        double a = (double)gb[e];
        for (int d = 0; d < 64; d++)
            a += (double)temb[tid * 64 + d] * (double)gw[(512 + d) * 8 + e];
        dtask[t] = a;
    }
    if (t < 8) out_task[t] = (float)task_id[t];
}

// ---------------- top-2 from raw logits ----------------
__global__ void __launch_bounds__(256) k_topk(const double* __restrict__ raw,
                                              const double* __restrict__ dmean,
                                              const double* __restrict__ drstd,
                                              const double* __restrict__ dcolsum,
                                              const double* __restrict__ dtask,
                                              int* __restrict__ hist,
                                              int2* __restrict__ route_e,
                                              float2* __restrict__ route_p,
                                              float* __restrict__ out_topk) {
    __shared__ int lh[8];
    int t = threadIdx.x;
    if (t < 8) lh[t] = 0;
    __syncthreads();
    int token = blockIdx.x * 256 + t;
    int b = token >> 12;
    double m = dmean[b], rs = drstd[b];
    double lg[8];
#pragma unroll
    for (int e = 0; e < 8; e++)
        lg[e] = rs * (raw[(size_t)token * 8 + e] - m * dcolsum[e]) + dtask[b * 8 + e];
    int i0 = 0;
#pragma unroll
    for (int e = 1; e < 8; e++) if (lg[e] > lg[i0]) i0 = e;
    int i1 = (i0 == 0) ? 1 : 0;
#pragma unroll
    for (int e = 0; e < 8; e++) if (e != i0 && lg[e] > lg[i1]) i1 = e;
    double d = exp(lg[i1] - lg[i0]);
    double p0 = 1.0 / (1.0 + d);
    double p1 = d / (1.0 + d);
    out_topk[token * 2]     = (float)i0;
    out_topk[token * 2 + 1] = (float)i1;
    atomicAdd(&lh[i0], 1);
    atomicAdd(&lh[i1], 1);
    route_e[token] = make_int2(i0, i1);
    route_p[token] = make_float2((float)p0, (float)p1);
    __syncthreads();
    if (t < 8) atomicAdd(&hist[t], lh[t]);
}

// ---------------- segment offsets (128-padded) + lb_loss ----------------
__global__ void k_offsets_lb(const int* __restrict__ hist, int* __restrict__ seg_off,
                             float* __restrict__ out_lb) {
    if (threadIdx.x == 0) {
        int off = 0;
        double ssd = 0.0;
        for (int e = 0; e < 8; e++) {
            seg_off[e] = off;
            off += (hist[e] + 127) & ~127;
            double d = (double)hist[e] - 8192.0;
            ssd += d * d;
        }
        seg_off[8] = off;
        double stdv = sqrt(ssd / 7.0);
        double m = 8192.0 + 1e-6;
        double r = stdv / m;
        *out_lb = (float)(r * r);
    }
}

// ---------------- scatter: LDS-aggregated two-level + inverse map ----------------
__global__ void __launch_bounds__(256) k_scatter(const int2* __restrict__ route_e,
                                                 const float2* __restrict__ route_p,
                                                 const int* __restrict__ seg_off,
                                                 int* __restrict__ cursor,
                                                 int* __restrict__ atok,
                                                 float* __restrict__ aprob,
                                                 int* __restrict__ tokpos) {
    __shared__ int lcount[8];
    __shared__ int lbase[8];
    int t = threadIdx.x;
    if (t < 8) lcount[t] = 0;
    __syncthreads();
    int tok = blockIdx.x * 256 + t;
    int2 e = route_e[tok];
    float2 p = route_p[tok];
    int p0 = atomicAdd(&lcount[e.x], 1);
    int p1 = atomicAdd(&lcount[e.y], 1);
    __syncthreads();
    if (t < 8) lbase[t] = atomicAdd(&cursor[t], lcount[t]);
    __syncthreads();
    int a0 = seg_off[e.x] + lbase[e.x] + p0;
    atok[a0] = tok; aprob[a0] = p.x;
    int a1 = seg_off[e.y] + lbase[e.y] + p1;
    atok[a1] = tok; aprob[a1] = p.y;
    tokpos[tok * 2]     = a0;
    tokpos[tok * 2 + 1] = a1;
}

// ============ MFMA GEMMs: r7-proven 2-phase double-buffered pipeline ============
// LDS: As[2]/Bs[2], XOR-swizzled [128][64] tiles staged via global_load_lds(16B).
// Per iter: issue next-tile stage -> s_waitcnt vmcnt(8) (counted; prefetch stays
// in flight) -> s_barrier -> ds_read+MFMA (setprio 1) -> s_barrier -> flip.
// mfma(bfv, af): lane's 4 acc elems = 4 consecutive OUTPUT COLUMNS.

// ---------------- GEMM1: H[chunk] = silu(X_gather @ w1[e] + b1[e]), full DFF ----------------
__global__ void __launch_bounds__(256) k_gemm1(const unsigned short* __restrict__ xb,
                                               const unsigned short* __restrict__ w1t,
                                               const float* __restrict__ b1,
                                               const int* __restrict__ atok,
                                               const int* __restrict__ seg_off,
                                               unsigned short* __restrict__ H,
                                               int t0) {
    int nwg = (int)gridDim.x;                       // TPC*16, multiple of 8
    int bid = (int)blockIdx.x;
    int wg = (bid & 7) * (nwg >> 3) + (bid >> 3);   // XCD-chunked logical id
    int xt = wg >> 4, y = wg & 15;                  // NY = 16
    int r0 = (t0 + xt) * 128;
    if (r0 >= seg_off[8]) return;
    int e = 0;
    while (seg_off[e + 1] <= r0) e++;
    int f0 = y * 128;

    int tid = threadIdx.x;
    int w = tid >> 6, l = tid & 63;
    int c = l & 7;

    __shared__ __align__(16) unsigned short As[2][128 * 64];
    __shared__ __align__(16) unsigned short Bs[2][128 * 64];

    const unsigned short* asrc[4];
    const unsigned short* bsrc[4];
    unsigned short*       adst[4];
    unsigned short*       bdst[4];
#pragma unroll
    for (int j = 0; j < 4; j++) {
        int R = w * 32 + j * 8 + (l >> 3);
        int cs = c ^ (R & 7);
        int tok = atok[r0 + R]; if (tok < 0) tok = 0;
        asrc[j] = xb + (size_t)tok * DM + cs * 8;
        bsrc[j] = w1t + ((size_t)e * DFF + f0 + R) * DM + cs * 8;
        adst[j] = &As[0][(size_t)(w * 32 + j * 8) * 64];
        bdst[j] = &Bs[0][(size_t)(w * 32 + j * 8) * 64];
    }

    f32x4 acc[4][4] = {};
    int wr = w >> 1, wc = w & 1, lr = l & 15, q = l >> 4;

    // prologue: stage k-step 0 into buffer 0
#pragma unroll
    for (int j = 0; j < 4; j++) { GLDS16(asrc[j], adst[j]); GLDS16(bsrc[j], bdst[j]); }

    int cur = 0;
    for (int it = 0; it < DM / 64; ++it) {          // 8 K-steps
        if (it + 1 < DM / 64) {
            int kn = (it + 1) * 64;
            int off = (cur ^ 1) * 128 * 64;
#pragma unroll
            for (int j = 0; j < 4; j++) {
                GLDS16(asrc[j] + kn, adst[j] + off);
                GLDS16(bsrc[j] + kn, bdst[j] + off);
            }
            asm volatile("s_waitcnt vmcnt(8)" ::: "memory");
        } else {
            asm volatile("s_waitcnt vmcnt(0)" ::: "memory");
        }
        __builtin_amdgcn_s_barrier();
        __builtin_amdgcn_sched_barrier(0);
        __builtin_amdgcn_s_setprio(1);
        const unsigned short* Ab = &As[cur][0];
        const unsigned short* Bb = &Bs[cur][0];
#pragma unroll
        for (int h = 0; h < 2; h++) {
            bf16x8 af[4], bfv[4];
#pragma unroll
            for (int m = 0; m < 4; m++) {
                int R = wr * 64 + m * 16 + lr;
                af[m] = *(const bf16x8*)&Ab[R * 64 + (((h << 2) + q) ^ (R & 7)) * 8];
            }
#pragma unroll
            for (int n = 0; n < 4; n++) {
                int R = wc * 64 + n * 16 + lr;
                bfv[n] = *(const bf16x8*)&Bb[R * 64 + (((h << 2) + q) ^ (R & 7)) * 8];
            }
#pragma unroll
            for (int m = 0; m < 4; m++)
#pragma unroll
                for (int n = 0; n < 4; n++)
                    acc[m][n] = __builtin_amdgcn_mfma_f32_16x16x32_bf16(bfv[n], af[m], acc[m][n], 0, 0, 0);
        }
        __builtin_amdgcn_s_setprio(0);
        __builtin_amdgcn_sched_barrier(0);
        asm volatile("" ::: "memory");
        __builtin_amdgcn_s_barrier();
        cur ^= 1;
    }

    // epilogue: acc[m][n][j] = H[r = wr*64+m*16+lr][f = f0 + wc*64 + n*16 + q*4 + j]
    const float* b1e = b1 + e * DFF + f0;
#pragma unroll
    for (int m = 0; m < 4; m++) {
        int r = wr * 64 + m * 16 + lr;
        unsigned short* hrow = H + ((size_t)xt * 128 + r) * DFF + f0;
#pragma unroll
        for (int n = 0; n < 4; n++) {
            int fc = wc * 64 + n * 16 + q * 4;
            float4 bias = *(const float4*)(b1e + fc);
            float v0 = acc[m][n][0] + bias.x; v0 = v0 / (1.0f + __expf(-v0));
            float v1 = acc[m][n][1] + bias.y; v1 = v1 / (1.0f + __expf(-v1));
            float v2 = acc[m][n][2] + bias.z; v2 = v2 / (1.0f + __expf(-v2));
            float v3 = acc[m][n][3] + bias.w; v3 = v3 / (1.0f + __expf(-v3));
            *(uint2*)(hrow + fc) = make_uint2(pkbf(v0, v1), pkbf(v2, v3));
        }
    }
}

// ---------------- GEMM2: Y[aidx] = H[chunk] @ w2[e]  (K=2048, plain bf16 stores) ----------------
__global__ void __launch_bounds__(256) k_gemm2(const unsigned short* __restrict__ H,
                                               const unsigned short* __restrict__ w2t,
                                               const int* __restrict__ seg_off,
                                               unsigned short* __restrict__ Y,
                                               int t0) {
    int nwg = (int)gridDim.x;                       // TPC*4, TPC even -> %8==0
    int bid = (int)blockIdx.x;
    int wg = (bid & 7) * (nwg >> 3) + (bid >> 3);
    int xt = wg >> 2, y = wg & 3;                   // NY = 4
    int r0 = (t0 + xt) * 128;
    if (r0 >= seg_off[8]) return;
    int e = 0;
    while (seg_off[e + 1] <= r0) e++;
    int d0 = y * 128;

    int tid = threadIdx.x;
    int w = tid >> 6, l = tid & 63;
    int c = l & 7;

    __shared__ __align__(16) unsigned short As[2][128 * 64];
    __shared__ __align__(16) unsigned short Bs[2][128 * 64];

    const unsigned short* asrc[4];
    const unsigned short* bsrc[4];
    unsigned short*       adst[4];
    unsigned short*       bdst[4];
#pragma unroll
    for (int j = 0; j < 4; j++) {
        int R = w * 32 + j * 8 + (l >> 3);
        int cs = c ^ (R & 7);
        asrc[j] = H + ((size_t)xt * 128 + R) * DFF + cs * 8;
        bsrc[j] = w2t + ((size_t)e * DM + d0 + R) * DFF + cs * 8;
        adst[j] = &As[0][(size_t)(w * 32 + j * 8) * 64];
        bdst[j] = &Bs[0][(size_t)(w * 32 + j * 8) * 64];
    }

    f32x4 acc[4][4] = {};
    int wr = w >> 1, wc = w & 1, lr = l & 15, q = l >> 4;

    // prologue
#pragma unroll
    for (int j = 0; j < 4; j++) { GLDS16(asrc[j], adst[j]); GLDS16(bsrc[j], bdst[j]); }

    int cur = 0;
    for (int it = 0; it < DFF / 64; ++it) {         // 32 K-steps
        if (it + 1 < DFF / 64) {
            int kn = (it + 1) * 64;
            int off = (cur ^ 1) * 128 * 64;
#pragma unroll
            for (int j = 0; j < 4; j++) {
                GLDS16(asrc[j] + kn, adst[j] + off);
                GLDS16(bsrc[j] + kn, bdst[j] + off);
            }
            asm volatile("s_waitcnt vmcnt(8)" ::: "memory");
        } else {
            asm volatile("s_waitcnt vmcnt(0)" ::: "memory");
        }
        __builtin_amdgcn_s_barrier();
        __builtin_amdgcn_sched_barrier(0);
        __builtin_amdgcn_s_setprio(1);
        const unsigned short* Ab = &As[cur][0];
        const unsigned short* Bb = &Bs[cur][0];
#pragma unroll
        for (int h = 0; h < 2; h++) {
            bf16x8 af[4], bfv[4];
#pragma unroll
            for (int m = 0; m < 4; m++) {
                int R = wr * 64 + m * 16 + lr;
                af[m] = *(const bf16x8*)&Ab[R * 64 + (((h << 2) + q) ^ (R & 7)) * 8];
            }
#pragma unroll
            for (int n = 0; n < 4; n++) {
                int R = wc * 64 + n * 16 + lr;
                bfv[n] = *(const bf16x8*)&Bb[R * 64 + (((h << 2) + q) ^ (R & 7)) * 8];
            }
#pragma unroll
            for (int m = 0; m < 4; m++)
#pragma unroll
                for (int n = 0; n < 4; n++)
                    acc[m][n] = __builtin_amdgcn_mfma_f32_16x16x32_bf16(bfv[n], af[m], acc[m][n], 0, 0, 0);
        }
        __builtin_amdgcn_s_setprio(0);
        __builtin_amdgcn_sched_barrier(0);
        asm volatile("" ::: "memory");
        __builtin_amdgcn_s_barrier();
        cur ^= 1;
    }

    // epilogue: acc[m][n][j] = Y[r = wr*64+m*16+lr][d = d0 + wc*64 + n*16 + q*4 + j]
#pragma unroll
    for (int m = 0; m < 4; m++) {
        int r = wr * 64 + m * 16 + lr;
        unsigned short* yrow = Y + (size_t)(r0 + r) * DM + d0;
#pragma unroll
        for (int n = 0; n < 4; n++) {
            int dc = wc * 64 + n * 16 + q * 4;
            *(uint2*)(yrow + dc) = make_uint2(pkbf(acc[m][n][0], acc[m][n][1]),
                                              pkbf(acc[m][n][2], acc[m][n][3]));
        }
    }
}

// ---------------- combine: out[t] = p0*(Y[a0]+b2[e0]) + p1*(Y[a1]+b2[e1]) ----------------
__global__ void __launch_bounds__(256) k_combine(const unsigned short* __restrict__ Y,
                                                 const float* __restrict__ b2,
                                                 const int* __restrict__ tokpos,
                                                 const int2* __restrict__ route_e,
                                                 const float2* __restrict__ route_p,
                                                 float* __restrict__ out) {
    int gt = blockIdx.x * 256 + threadIdx.x;
    int token = gt >> 6;
    int cbase = (gt & 63) * 8;
    int2 e = route_e[token];
    float2 p = route_p[token];
    int a0 = tokpos[token * 2], a1 = tokpos[token * 2 + 1];
    s16x8 y0 = *(const s16x8*)(Y + (size_t)a0 * DM + cbase);
    s16x8 y1 = *(const s16x8*)(Y + (size_t)a1 * DM + cbase);
    const float4* bb0 = (const float4*)(b2 + e.x * DM + cbase);
    const float4* bb1 = (const float4*)(b2 + e.y * DM + cbase);
    float4 b00 = bb0[0], b01 = bb0[1];
    float4 b10 = bb1[0], b11 = bb1[1];
    float r[8];
    r[0] = p.x * (bf2f((unsigned short)y0[0]) + b00.x) + p.y * (bf2f((unsigned short)y1[0]) + b10.x);
    r[1] = p.x * (bf2f((unsigned short)y0[1]) + b00.y) + p.y * (bf2f((unsigned short)y1[1]) + b10.y);
    r[2] = p.x * (bf2f((unsigned short)y0[2]) + b00.z) + p.y * (bf2f((unsigned short)y1[2]) + b10.z);
    r[3] = p.x * (bf2f((unsigned short)y0[3]) + b00.w) + p.y * (bf2f((unsigned short)y1[3]) + b10.w);
    r[4] = p.x * (bf2f((unsigned short)y0[4]) + b01.x) + p.y * (bf2f((unsigned short)y1[4]) + b11.x);
    r[5] = p.x * (bf2f((unsigned short)y0[5]) + b01.y) + p.y * (bf2f((unsigned short)y1[5]) + b11.y);
    r[6] = p.x * (bf2f((unsigned short)y0[6]) + b01.z) + p.y * (bf2f((unsigned short)y1[6]) + b11.z);
    r[7] = p.x * (bf2f((unsigned short)y0[7]) + b01.w) + p.y * (bf2f((unsigned short)y1[7]) + b11.w);
    float* op = out + (size_t)token * DM + cbase;
    *(float4*)op       = make_float4(r[0], r[1], r[2], r[3]);
    *(float4*)(op + 4) = make_float4(r[4], r[5], r[6], r[7]);
}

// ---------------- launch ----------------
extern "C" void kernel_launch(void* const* d_in, const int* in_sizes, int n_in,
                              void* d_out, int out_size, void* d_ws, size_t ws_size,
                              hipStream_t stream) {
    const float* x       = (const float*)d_in[0];
    const int*   task_id = (const int*)d_in[1];
    const float* w1      = (const float*)d_in[2];
    const float* b1      = (const float*)d_in[3];
    const float* w2      = (const float*)d_in[4];
    const float* b2      = (const float*)d_in[5];
    const float* temb    = (const float*)d_in[6];
    const float* gw      = (const float*)d_in[7];
    const float* gb      = (const float*)d_in[8];
    float* out = (float*)d_out;

    char* ws = (char*)d_ws;
    double* bstats   = (double*)(ws + WS_BSTATS);
    double* dmean    = (double*)(ws + WS_DMEAN);
    double* drstd    = (double*)(ws + WS_DRSTD);
    double* dcolsum  = (double*)(ws + WS_DCOLSUM);
    double* dtask    = (double*)(ws + WS_DTASK);
    int*    hist     = (int*)(ws + WS_HIST);
    int*    cursor   = (int*)(ws + WS_CURSOR);
    int*    seg_off  = (int*)(ws + WS_SEGOFF);
    int2*   route_e  = (int2*)(ws + WS_ROUTE_E);
    float2* route_p  = (float2*)(ws + WS_ROUTE_P);
    int*    atok     = (int*)(ws + WS_ATOK);
    float*  aprob    = (float*)(ws + WS_APROB);
    int*    tokpos   = (int*)(ws + WS_TOKPOS);
    double* raw      = (double*)(ws + WS_RAW);
    unsigned short* w1t = (unsigned short*)(ws + WS_W1T);
    unsigned short* w2t = (unsigned short*)(ws + WS_W2T);
    unsigned short* xb  = (unsigned short*)(ws + WS_XB);
    unsigned short* Y   = (unsigned short*)(ws + WS_Y);
    unsigned short* H   = (unsigned short*)(ws + WS_H);

    // 128-row tiles per chunk. Cap at 128 so grids quantize exactly to the
    // 512-block concurrency limit (2 blocks/CU x 256 CU at 64 KB LDS):
    // gemm1 grid = 16*TPC = 2048 (4 exact rounds), gemm2 grid = 4*TPC = 512 (1 round).
    int TPC = (int)((ws_size - (size_t)WS_H) / (size_t)(128 * DFF * 2));
    if (TPC > 128) TPC = 128;
    TPC &= ~1;
    if (TPC < 2) TPC = 2;

    hipMemsetAsync(ws, 0, WS_HDR_END, stream);
    hipMemsetAsync(ws + WS_ATOK, 0xFF, (size_t)MAXROWS * sizeof(int), stream);

    k_transpose_bf16<<<dim3(DFF / 32, DM / 32, NE), 256, 0, stream>>>(w1, w1t, DM, DFF);
    k_transpose_bf16<<<dim3(DM / 32, DFF / 32, NE), 256, 0, stream>>>(w2, w2t, DFF, DM);

    // fused gate-raw + x->bf16 + stats (single pass over x, 4 threads/token)
    k_xgate<<<NTOK / 64, 256, 0, stream>>>(x, gw, xb, bstats, raw);
    k_finalize<<<1, 256, 0, stream>>>(bstats, dmean, drstd, dcolsum, dtask,
                                      gw, gb, temb, task_id, out + OUT_TASK);
    k_topk<<<NTOK / 256, 256, 0, stream>>>(raw, dmean, drstd, dcolsum, dtask,
                                           hist, route_e, route_p, out + OUT_TOPK);
    k_offsets_lb<<<1, 64, 0, stream>>>(hist, seg_off, out + OUT_LB);
    k_scatter<<<NTOK / 256, 256, 0, stream>>>(route_e, route_p, seg_off, cursor,
                                              atok, aprob, tokpos);

    for (int t0 = 0; t0 < MAXTILES; t0 += TPC) {
        k_gemm1<<<TPC * 16, 256, 0, stream>>>(xb, w1t, b1, atok, seg_off, H, t0);
        k_gemm2<<<TPC * 4, 256, 0, stream>>>(H, w2t, seg_off, Y, t0);
    }
    k_combine<<<NTOK / 4, 256, 0, stream>>>(Y, b2, tokpos, route_e, route_p, out);
}